// Round 3
// baseline (798.466 us; speedup 1.0000x reference)
//
#include <hip/hip_runtime.h>
#include <math.h>

// ---- problem dims ----
#define BB   16
#define SS   8
#define TKK  400
#define HH   256
#define EE   128
#define VV   50000
#define OOVV 50
#define HH2  512
#define STK  (SS*TKK)     // 3200
#define VOO  (VV+OOVV)    // 50050
#define NVBLK 196         // ceil(50000/256)

// ---- workspace offsets (floats) ----
#define OFF_X     0        // B*E      = 2048
#define OFF_ST    2048     // B*H2     = 8192   s_t_hat = [h,c]
#define OFF_SD    10240    // B*H2     = 8192
#define OFF_WD    18432    // B*H2     = 8192
#define OFF_BETA  26624    // unused (beta inlined in k_attn)
#define OFF_SCSEC 26752    // B*S      = 128 (zeroed in k_bt, atomic accum)
#define OFF_SCW   26880    // B*S*TK   = 51200 (plain stores from k_gemm3)
#define OFF_CT    78080    // B*H2     = 8192  (zeroed in k_attn, atomic accum)
#define OFF_OUT1  86272    // B*H      = 4096
#define OFF_PGEN  90368    // B        = 16
#define OFF_PMAX  90384    // NVBLK*B  = 3136
#define OFF_PSUM  93520    // NVBLK*B  = 3136
#define OFF_GATES 96656    // B*4H     = 16384
#define OFF_BT    113040   // 512*512 bf16 = 131072 float-slots (16B aligned)

// ---- output offsets (floats) ----
#define O_FD   0
#define O_H    800800
#define O_C    804896
#define O_CT   808992
#define O_ATTN 817184
#define O_PGEN 868384
#define O_COV  868400

typedef __attribute__((ext_vector_type(8))) short bf16x8;
typedef __attribute__((ext_vector_type(4))) float f32x4;

__device__ __forceinline__ float sigm(float x){ return 1.0f/(1.0f+expf(-x)); }

__device__ __forceinline__ unsigned short f2b(float f){
  unsigned int u = __float_as_uint(f);
  unsigned int r = (u + 0x7fffu + ((u >> 16) & 1u)) >> 16;
  return (unsigned short)r;
}

__device__ __forceinline__ float wave_sum(float v){
  #pragma unroll
  for(int o=32;o>0;o>>=1) v += __shfl_xor(v,o);
  return v;
}
__device__ __forceinline__ float wave_max(float v){
  #pragma unroll
  for(int o=32;o>0;o>>=1) v = fmaxf(v,__shfl_xor(v,o));
  return v;
}

// transpose Whw [512k][512n] fp32 -> Bt [512n][512k] bf16; zero SCSEC.  grid (8,8) x 256
__global__ void k_bt(const float* __restrict__ Whw, unsigned short* __restrict__ Bt,
                     float* __restrict__ ws){
  __shared__ float tile[64][65];
  if(blockIdx.x==0 && blockIdx.y==0 && threadIdx.x < BB*SS)
    ws[OFF_SCSEC + threadIdx.x] = 0.0f;
  int n0 = blockIdx.x*64, k0 = blockIdx.y*64;
  int tx = threadIdx.x & 63, ty = threadIdx.x >> 6;  // ty 0..3
  #pragma unroll
  for(int it=0; it<16; it++){
    int kk = it*4 + ty;
    tile[kk][tx] = Whw[(size_t)(k0+kk)*HH2 + n0 + tx];
  }
  __syncthreads();
  #pragma unroll
  for(int it=0; it<16; it++){
    int nn = it*4 + ty;
    Bt[(size_t)(n0+nn)*HH2 + k0 + tx] = f2b(tile[tx][nn]);
  }
}

// x = [c_t_1, emb[y]] @ W_xc + b_xc   grid 16 x 128
__global__ void k_x(const int* __restrict__ y, const float* __restrict__ ct1,
                    const float* __restrict__ emb, const float* __restrict__ Wxc,
                    const float* __restrict__ bxc, float* __restrict__ ws){
  int b = blockIdx.x, e = threadIdx.x;
  __shared__ float cat[HH2+EE];
  for(int k=e;k<HH2;k+=EE) cat[k] = ct1[b*HH2+k];
  int tok = y[b];
  cat[HH2+e] = emb[(size_t)tok*EE + e];
  __syncthreads();
  float acc = bxc[e];
  for(int k=0;k<HH2+EE;k++) acc += cat[k]*Wxc[k*EE+e];
  ws[OFF_X + b*EE + e] = acc;
}

// gates[b][c] = x[b]@Wih[:,c] + h0[b]@Whh[:,c] + bih[c]+bhh[c]
// grid 8 x 256: block owns 128 gate-cols for ALL 16 b (16 FMA per weight load)
__global__ void k_gates(const float* __restrict__ h0,
                        const float* __restrict__ Wih, const float* __restrict__ bih,
                        const float* __restrict__ Whh, const float* __restrict__ bhh,
                        float* __restrict__ ws){
  int tid = threadIdx.x;
  int n = tid & 127, bg = tid >> 7;          // bg 0..1 -> 8 b each
  int c = blockIdx.x*128 + n;
  __shared__ float xs[BB*EE];    // 8 KB
  __shared__ float hs[BB*HH];    // 16 KB
  for(int f=tid; f<BB*EE; f+=256) xs[f] = ws[OFF_X + f];
  for(int f=tid; f<BB*HH; f+=256) hs[f] = h0[f];
  __syncthreads();
  float acc[8];
  float bias = bih[c] + bhh[c];
  #pragma unroll
  for(int i=0;i<8;i++) acc[i] = bias;
  for(int k=0;k<EE;k++){
    float w = Wih[k*4*HH + c];
    #pragma unroll
    for(int i=0;i<8;i++) acc[i] += xs[(bg*8+i)*EE + k]*w;
  }
  for(int k=0;k<HH;k++){
    float w = Whh[k*4*HH + c];
    #pragma unroll
    for(int i=0;i<8;i++) acc[i] += hs[(bg*8+i)*HH + k]*w;
  }
  #pragma unroll
  for(int i=0;i<8;i++) ws[OFF_GATES + (bg*8+i)*4*HH + c] = acc[i];
}

// LSTM pointwise -> h, c, s_t_hat.  grid 16 x 256
__global__ void k_hc(const float* __restrict__ c0, float* __restrict__ ws,
                     float* __restrict__ out){
  int b = blockIdx.x, j = threadIdx.x;
  const float* g = &ws[OFF_GATES + b*4*HH];
  float ig = sigm(g[j]), fg = sigm(g[HH+j]), gg = tanhf(g[2*HH+j]), og = sigm(g[3*HH+j]);
  float c = fg*c0[b*HH+j] + ig*gg;
  float h = og*tanhf(c);
  out[O_H + b*HH + j] = h;
  out[O_C + b*HH + j] = c;
  ws[OFF_ST + b*HH2 + j]      = h;
  ws[OFF_ST + b*HH2 + HH + j] = c;
}

// sd/wd projections, batched over b.  grid (4 chunk, 2 mat) x 256
__global__ void k_proj(const float* __restrict__ Wdsec, const float* __restrict__ bdsec,
                       const float* __restrict__ Wdw,  const float* __restrict__ bdw,
                       float* __restrict__ ws){
  int tid = threadIdx.x;
  int n = tid & 127, bg = tid >> 7;
  int c = blockIdx.x*128 + n;
  const float* Wm; const float* bias; int dst;
  if(blockIdx.y==0){ Wm=Wdsec; bias=bdsec; dst=OFF_SD; }
  else             { Wm=Wdw;   bias=bdw;   dst=OFF_WD; }
  __shared__ float st[BB*HH2];   // 32 KB
  for(int f=tid; f<BB*HH2; f+=256) st[f] = ws[OFF_ST + f];
  __syncthreads();
  float acc[8];
  float bv = bias[c];
  #pragma unroll
  for(int i=0;i<8;i++) acc[i] = bv;
  for(int k=0;k<HH2;k++){
    float w = Wm[k*HH2 + c];
    #pragma unroll
    for(int i=0;i<8;i++) acc[i] += st[(bg*8+i)*HH2 + k]*w;
  }
  #pragma unroll
  for(int i=0;i<8;i++) ws[dst + (bg*8+i)*HH2 + c] = acc[i];
}

// section attention scores, batched over b.  grid (8 s, 8 chunk64) x 256
__global__ void k_esec(const float* __restrict__ sec, const float* __restrict__ Whsec,
                       const float* __restrict__ vsec, float* __restrict__ ws){
  int tid = threadIdx.x;
  int s = blockIdx.x;
  int n = tid & 63, bg = tid >> 6;           // bg 0..3 -> 4 b each (one wave per bg)
  int c = blockIdx.y*64 + n;
  __shared__ float rows[BB*HH2];   // 32 KB
  for(int t=0;t<32;t++){
    int f = tid + 256*t;
    int bb = f >> 9, kk = f & 511;
    rows[f] = sec[(size_t)(bb*SS + s)*HH2 + kk];
  }
  __syncthreads();
  float acc[4] = {0,0,0,0};
  for(int k=0;k<HH2;k++){
    float w = Whsec[k*HH2 + c];
    #pragma unroll
    for(int i=0;i<4;i++) acc[i] += rows[(bg*4+i)*HH2 + k]*w;
  }
  float vs = vsec[c];
  #pragma unroll
  for(int i=0;i<4;i++){
    int b = bg*4 + i;
    float v = tanhf(acc[i] + ws[OFF_SD + b*HH2 + c]) * vs;
    v = wave_sum(v);
    if(n==0) atomicAdd(&ws[OFF_SCSEC + b*SS + s], v);
  }
}

// MFMA fused GEMM, double-buffered LDS with register prefetch.
// sc_w[row] = sum_n tanh(enc[row,:]@Whw[:,n] + wd[b,n] + cov[row]*Wc_w[n]) * vw[n]
// grid 800 x 256 (64 rows/block, all 512 cols in 4 chunks, K=512 in 8 steps)
__global__ __launch_bounds__(256,3) void k_gemm3(
        const float* __restrict__ A, const unsigned short* __restrict__ Bt,
        const float* __restrict__ Wcw, const float* __restrict__ vw,
        const float* __restrict__ cover, float* __restrict__ ws){
  __shared__ __align__(16) unsigned short As[2][64*64];
  __shared__ __align__(16) unsigned short Bs[2][128*64];
  int tid = threadIdx.x;
  int w = tid >> 6, lane = tid & 63;
  int m = lane & 15, q = lane >> 4;
  int mh = m & 7;                       // XOR-swizzle key
  int row0 = blockIdx.x * 64;
  int b = blockIdx.x / 50;              // 50 blocks per batch
  float cov[4];
  #pragma unroll
  for(int r=0;r<4;r++) cov[r] = cover[row0 + w*16 + q*4 + r];
  float rsum[4] = {0,0,0,0};
  f32x4 acc[8];
  #pragma unroll
  for(int j=0;j<8;j++) acc[j] = (f32x4){0.f,0.f,0.f,0.f};

  float4 pa[4]; bf16x8 pb[4];
  // prefetch round 0
  #pragma unroll
  for(int p=0;p<2;p++){
    int c = tid + 256*p; int r = c>>3; int kc = (c&7)*8;
    const float4* src = (const float4*)&A[(size_t)(row0+r)*HH2 + kc];
    pa[2*p] = src[0]; pa[2*p+1] = src[1];
  }
  #pragma unroll
  for(int p=0;p<4;p++){
    int c = tid + 256*p; int r = c>>3; int kc = (c&7)*8;
    pb[p] = *(const bf16x8*)&Bt[(size_t)r*HH2 + kc];
  }
  // store round 0 -> buf 0
  #pragma unroll
  for(int p=0;p<2;p++){
    int c = tid + 256*p; int r = c>>3; int sc = 8*((c&7) ^ (r&7));
    union{ bf16x8 v; unsigned short u[8]; } t;
    float4 v0 = pa[2*p], v1 = pa[2*p+1];
    t.u[0]=f2b(v0.x); t.u[1]=f2b(v0.y); t.u[2]=f2b(v0.z); t.u[3]=f2b(v0.w);
    t.u[4]=f2b(v1.x); t.u[5]=f2b(v1.y); t.u[6]=f2b(v1.z); t.u[7]=f2b(v1.w);
    *(bf16x8*)&As[0][r*64 + sc] = t.v;
  }
  #pragma unroll
  for(int p=0;p<4;p++){
    int c = tid + 256*p; int r = c>>3; int sc = 8*((c&7) ^ (r&7));
    *(bf16x8*)&Bs[0][r*64 + sc] = pb[p];
  }
  __syncthreads();

  for(int rnd=0; rnd<32; rnd++){
    int cur = rnd & 1;
    if(rnd < 31){
      int nr = rnd + 1;
      int k0 = (nr & 7) * 64;
      int col0 = (nr >> 3) * 128;
      #pragma unroll
      for(int p=0;p<2;p++){
        int c = tid + 256*p; int r = c>>3; int kc = (c&7)*8;
        const float4* src = (const float4*)&A[(size_t)(row0+r)*HH2 + k0 + kc];
        pa[2*p] = src[0]; pa[2*p+1] = src[1];
      }
      #pragma unroll
      for(int p=0;p<4;p++){
        int c = tid + 256*p; int r = c>>3; int kc = (c&7)*8;
        pb[p] = *(const bf16x8*)&Bt[(size_t)(col0+r)*HH2 + k0 + kc];
      }
    }
    // compute on LDS[cur]
    #pragma unroll
    for(int kk8=0; kk8<2; kk8++){
      bf16x8 af = *(bf16x8*)&As[cur][(w*16+m)*64 + 8*((kk8*4+q) ^ mh)];
      #pragma unroll
      for(int j=0;j<8;j++){
        bf16x8 bf = *(bf16x8*)&Bs[cur][(j*16+m)*64 + 8*((kk8*4+q) ^ mh)];
        acc[j] = __builtin_amdgcn_mfma_f32_16x16x32_bf16(af, bf, acc[j], 0,0,0);
      }
    }
    if(rnd < 31){
      int nb = cur ^ 1;
      #pragma unroll
      for(int p=0;p<2;p++){
        int c = tid + 256*p; int r = c>>3; int sc = 8*((c&7) ^ (r&7));
        union{ bf16x8 v; unsigned short u[8]; } t;
        float4 v0 = pa[2*p], v1 = pa[2*p+1];
        t.u[0]=f2b(v0.x); t.u[1]=f2b(v0.y); t.u[2]=f2b(v0.z); t.u[3]=f2b(v0.w);
        t.u[4]=f2b(v1.x); t.u[5]=f2b(v1.y); t.u[6]=f2b(v1.z); t.u[7]=f2b(v1.w);
        *(bf16x8*)&As[nb][r*64 + sc] = t.v;
      }
      #pragma unroll
      for(int p=0;p<4;p++){
        int c = tid + 256*p; int r = c>>3; int sc = 8*((c&7) ^ (r&7));
        *(bf16x8*)&Bs[nb][r*64 + sc] = pb[p];
      }
    }
    if((rnd & 7) == 7){
      int col0 = (rnd >> 3) * 128;
      #pragma unroll
      for(int j=0;j<8;j++){
        int col = col0 + j*16 + m;
        float wdv = ws[OFF_WD + b*HH2 + col];
        float wcv = Wcw[col], vwv = vw[col];
        #pragma unroll
        for(int r=0;r<4;r++)
          rsum[r] += tanhf(acc[j][r] + wdv + cov[r]*wcv) * vwv;
        acc[j] = (f32x4){0.f,0.f,0.f,0.f};
      }
    }
    __syncthreads();
  }
  #pragma unroll
  for(int r=0;r<4;r++){
    float v = rsum[r];
    v += __shfl_xor(v,1,16); v += __shfl_xor(v,2,16);
    v += __shfl_xor(v,4,16); v += __shfl_xor(v,8,16);
    if(m==0) ws[OFF_SCW + row0 + w*16 + q*4 + r] = v;
  }
}

// beta (inline) + attn softmax over 3200 + mask + renorm + coverage out + zero CT.
// grid 16 x 256
__global__ void k_attn(const float* __restrict__ mask, const float* __restrict__ cover,
                       float* __restrict__ ws, float* __restrict__ out){
  int b = blockIdx.x, tid = threadIdx.x;
  __shared__ float vals[STK];
  __shared__ float red[4];
  __shared__ float sc[SS];
  if(tid < SS) sc[tid] = ws[OFF_SCSEC + b*SS + tid];
  for(int k=tid;k<HH2;k+=256) ws[OFF_CT + b*HH2 + k] = 0.0f;
  __syncthreads();
  // beta = softmax(sc) (double-normalize == single in exact math)
  float bm = -1e30f;
  #pragma unroll
  for(int s=0;s<SS;s++) bm = fmaxf(bm, sc[s]);
  float be[SS]; float bsum = 0.0f;
  #pragma unroll
  for(int s=0;s<SS;s++){ be[s] = expf(sc[s]-bm); bsum += be[s]; }
  #pragma unroll
  for(int s=0;s<SS;s++) be[s] /= bsum;
  int lane = tid & 63, w = tid >> 6;
  float m = -1e30f;
  for(int j=tid;j<STK;j+=256){
    float v = be[j/TKK] * ws[OFF_SCW + b*STK + j];
    vals[j] = v; m = fmaxf(m, v);
  }
  m = wave_max(m);
  if(lane==0) red[w] = m;
  __syncthreads();
  m = fmaxf(fmaxf(red[0],red[1]), fmaxf(red[2],red[3]));
  __syncthreads();
  float ssum = 0.0f;
  for(int j=tid;j<STK;j+=256){
    float e = expf(vals[j]-m) * mask[b*STK + j];
    vals[j] = e; ssum += e;
  }
  ssum = wave_sum(ssum);
  if(lane==0) red[w] = ssum;
  __syncthreads();
  float inv = 1.0f/(red[0]+red[1]+red[2]+red[3]);
  for(int j=tid;j<STK;j+=256){
    float a = vals[j]*inv;
    out[O_ATTN + b*STK + j] = a;
    out[O_COV  + b*STK + j] = cover[b*STK + j] + a;
  }
}

// c_t = attn @ enc.  grid (50,16) x 256, atomic accumulate
__global__ void k_ct(const float* __restrict__ enc, const float* __restrict__ out,
                     float* __restrict__ ws){
  int b = blockIdx.y, tid = threadIdx.x;
  __shared__ float a[64];
  int t0 = blockIdx.x*64;
  if(tid<64) a[tid] = out[O_ATTN + b*STK + t0 + tid];
  __syncthreads();
  float acc0=0.0f, acc1=0.0f;
  #pragma unroll 4
  for(int tt=0;tt<64;tt++){
    const float* row = &enc[(size_t)(b*STK + t0 + tt)*HH2];
    float av = a[tt];
    acc0 += av*row[tid];
    acc1 += av*row[256+tid];
  }
  atomicAdd(&ws[OFF_CT + b*HH2 + tid],       acc0);
  atomicAdd(&ws[OFF_CT + b*HH2 + 256 + tid], acc1);
}

// out1 (batched over b) + p_gen + c_t output copy.  grid 2 x 256
__global__ void k_out1(const float* __restrict__ Wp, const float* __restrict__ bp,
                       const float* __restrict__ Wo1, const float* __restrict__ bo1,
                       float* __restrict__ ws, float* __restrict__ out){
  int tid = threadIdx.x;
  int n = tid & 127, bg = tid >> 7;
  int c = blockIdx.x*128 + n;
  __shared__ float cat[BB*768];   // [b][ h(256) | ct(512) ] = 48 KB
  for(int t=0;t<48;t++){
    int f = tid + 256*t;
    int b = f / 768, r = f - b*768;
    cat[f] = (r < HH) ? ws[OFF_ST + b*HH2 + r] : ws[OFF_CT + b*HH2 + (r-HH)];
  }
  __syncthreads();
  float acc[8];
  float bv = bo1[c];
  #pragma unroll
  for(int i=0;i<8;i++) acc[i] = bv;
  for(int k=0;k<HH;k++){
    float w = Wo1[k*HH + c];
    #pragma unroll
    for(int i=0;i<8;i++) acc[i] += cat[(bg*8+i)*768 + k]*w;
  }
  for(int k=0;k<HH2;k++){
    float w = Wo1[(HH+k)*HH + c];
    #pragma unroll
    for(int i=0;i<8;i++) acc[i] += cat[(bg*8+i)*768 + HH + k]*w;
  }
  #pragma unroll
  for(int i=0;i<8;i++) ws[OFF_OUT1 + (bg*8+i)*HH + c] = acc[i];
  if(blockIdx.x == 0){
    // p_gen: wave v handles b = v*4..v*4+3, direct global reads (tiny)
    int lane = tid & 63, wv = tid >> 6;
    #pragma unroll
    for(int i=0;i<4;i++){
      int b = wv*4 + i;
      float p = 0.0f;
      for(int k=lane;k<4*HH+EE;k+=64){
        float val = (k < HH2) ? ws[OFF_CT + b*HH2 + k]
                  : (k < 4*HH) ? ws[OFF_ST + b*HH2 + (k-HH2)]
                  : ws[OFF_X + b*EE + (k-4*HH)];
        p += val * Wp[k];
      }
      p = wave_sum(p);
      if(lane==0){
        float pg = sigm(p + bp[0]);
        ws[OFF_PGEN + b] = pg;
        out[O_PGEN + b]  = pg;
      }
    }
  } else {
    for(int f=tid; f<BB*HH2; f+=256){
      int b = f >> 9, j = f & 511;
      out[O_CT + f] = cat[b*768 + HH + j];
    }
  }
}

// logits -> final_dist area (in place), per-block per-b max.  grid 196 x 256
__global__ void k_logits(const float* __restrict__ W2, const float* __restrict__ b2,
                         float* __restrict__ ws, float* __restrict__ out){
  int tid = threadIdx.x;
  int c = blockIdx.x*256 + tid;
  __shared__ float o1[BB*HH];   // 16 KB
  __shared__ float lmax[4*BB];
  for(int i=tid;i<BB*HH;i+=256) o1[i] = ws[OFF_OUT1 + i];
  __syncthreads();
  bool ok = c < VV;
  float acc[BB] = {};
  if(ok){
    for(int k=0;k<HH;k++){
      float wv = W2[(size_t)k*VV + c];
      #pragma unroll
      for(int bb=0;bb<BB;bb++) acc[bb] += o1[bb*HH+k]*wv;
    }
  }
  float bias = ok ? b2[c] : 0.0f;
  int lane = tid & 63, w = tid >> 6;
  #pragma unroll
  for(int bb=0;bb<BB;bb++){
    float v = ok ? (acc[bb]+bias) : -1e30f;
    if(ok) out[(size_t)bb*VOO + c] = v;
    float mv = wave_max(v);
    if(lane==0) lmax[w*BB+bb] = mv;
  }
  __syncthreads();
  if(tid < BB){
    float m = fmaxf(fmaxf(lmax[tid],lmax[BB+tid]), fmaxf(lmax[2*BB+tid],lmax[3*BB+tid]));
    ws[OFF_PMAX + blockIdx.x*BB + tid] = m;
  }
}

// exp(logit - max) in place + per-block per-b sums.  grid 196 x 256
__global__ void k_vexp(float* __restrict__ ws, float* __restrict__ out){
  int tid = threadIdx.x;
  int c = blockIdx.x*256 + tid;
  __shared__ float vmax[BB];
  __shared__ float lsum[4*BB];
  if(tid < BB){
    float m = -1e30f;
    for(int i=0;i<NVBLK;i++) m = fmaxf(m, ws[OFF_PMAX + i*BB + tid]);
    vmax[tid] = m;
  }
  __syncthreads();
  bool ok = c < VV;
  int lane = tid & 63, w = tid >> 6;
  #pragma unroll
  for(int bb=0;bb<BB;bb++){
    float e = 0.0f;
    if(ok){
      e = expf(out[(size_t)bb*VOO + c] - vmax[bb]);
      out[(size_t)bb*VOO + c] = e;
    }
    float sv = wave_sum(e);
    if(lane==0) lsum[w*BB+bb] = sv;
  }
  __syncthreads();
  if(tid < BB){
    ws[OFF_PSUM + blockIdx.x*BB + tid] =
      lsum[tid] + lsum[BB+tid] + lsum[2*BB+tid] + lsum[3*BB+tid];
  }
}

// final_dist = p_gen * e / sum  (v < V), extra_zeros tail.  grid (196,16) x 256
__global__ void k_final(const float* __restrict__ xz, float* __restrict__ ws,
                        float* __restrict__ out){
  int b = blockIdx.y;
  int v = blockIdx.x*256 + threadIdx.x;
  __shared__ float red[4];
  int lane = threadIdx.x & 63, w = threadIdx.x >> 6;
  float p = 0.0f;
  for(int i=threadIdx.x;i<NVBLK;i+=256) p += ws[OFF_PSUM + i*BB + b];
  p = wave_sum(p);
  if(lane==0) red[w] = p;
  __syncthreads();
  float s = red[0]+red[1]+red[2]+red[3];
  float pg = ws[OFF_PGEN + b];
  if(v < VV)       out[(size_t)b*VOO + v] = pg * out[(size_t)b*VOO + v] / s;
  else if(v < VOO) out[(size_t)b*VOO + v] = xz[b*OOVV + (v-VV)];
}

// scatter-add (1-p_gen)*attn at extend-vocab indices.  grid 16 x 256
__global__ void k_scatter(const int* __restrict__ ebev, float* __restrict__ ws,
                          float* __restrict__ out){
  int b = blockIdx.x;
  float r = 1.0f - ws[OFF_PGEN + b];
  for(int j=threadIdx.x;j<STK;j+=256){
    int idx = ebev[b*STK + j];
    atomicAdd(&out[(size_t)b*VOO + idx], r*out[O_ATTN + b*STK + j]);
  }
}

extern "C" void kernel_launch(void* const* d_in, const int* in_sizes, int n_in,
                              void* d_out, int out_size, void* d_ws, size_t ws_size,
                              hipStream_t stream){
  const int*   y     = (const int*)  d_in[0];
  const float* h0    = (const float*)d_in[1];
  const float* c0    = (const float*)d_in[2];
  const float* enc   = (const float*)d_in[3];
  const float* sec   = (const float*)d_in[4];
  const float* mask  = (const float*)d_in[5];
  const float* ct1   = (const float*)d_in[6];
  const float* xz    = (const float*)d_in[7];
  const int*   ebev  = (const int*)  d_in[8];
  const float* cover = (const float*)d_in[9];
  /* d_in[10] = gamma (unused by reference) */
  const float* emb   = (const float*)d_in[11];
  const float* Wxc   = (const float*)d_in[12];
  const float* bxc   = (const float*)d_in[13];
  const float* Wih   = (const float*)d_in[14];
  const float* bih   = (const float*)d_in[15];
  const float* Whh   = (const float*)d_in[16];
  const float* bhh   = (const float*)d_in[17];
  const float* Whsec = (const float*)d_in[18];
  const float* Wdsec = (const float*)d_in[19];
  const float* bdsec = (const float*)d_in[20];
  const float* vsec  = (const float*)d_in[21];
  const float* Whw   = (const float*)d_in[22];
  const float* Wcw   = (const float*)d_in[23];
  const float* Wdw   = (const float*)d_in[24];
  const float* bdw   = (const float*)d_in[25];
  const float* vw    = (const float*)d_in[26];
  const float* Wp    = (const float*)d_in[27];
  const float* bp    = (const float*)d_in[28];
  const float* Wo1   = (const float*)d_in[29];
  const float* bo1   = (const float*)d_in[30];
  const float* Wo2   = (const float*)d_in[31];
  const float* bo2   = (const float*)d_in[32];
  float* out = (float*)d_out;
  float* ws  = (float*)d_ws;
  unsigned short* Bt = (unsigned short*)(ws + OFF_BT);

  k_bt     <<<dim3(8,8),      dim3(256), 0, stream>>>(Whw, Bt, ws);
  k_x      <<<dim3(BB),       dim3(128), 0, stream>>>(y, ct1, emb, Wxc, bxc, ws);
  k_gates  <<<dim3(8),        dim3(256), 0, stream>>>(h0, Wih, bih, Whh, bhh, ws);
  k_hc     <<<dim3(BB),       dim3(256), 0, stream>>>(c0, ws, out);
  k_proj   <<<dim3(4,2),      dim3(256), 0, stream>>>(Wdsec, bdsec, Wdw, bdw, ws);
  k_esec   <<<dim3(SS,8),     dim3(256), 0, stream>>>(sec, Whsec, vsec, ws);
  k_gemm3  <<<dim3(800),      dim3(256), 0, stream>>>(enc, Bt, Wcw, vw, cover, ws);
  k_attn   <<<dim3(BB),       dim3(256), 0, stream>>>(mask, cover, ws, out);
  k_ct     <<<dim3(50,BB),    dim3(256), 0, stream>>>(enc, out, ws);
  k_out1   <<<dim3(2),        dim3(256), 0, stream>>>(Wp, bp, Wo1, bo1, ws, out);
  k_logits <<<dim3(NVBLK),    dim3(256), 0, stream>>>(Wo2, bo2, ws, out);
  k_vexp   <<<dim3(NVBLK),    dim3(256), 0, stream>>>(ws, out);
  k_final  <<<dim3(NVBLK,BB), dim3(256), 0, stream>>>(xz, ws, out);
  k_scatter<<<dim3(BB),       dim3(256), 0, stream>>>(ebev, ws, out);
}

// Round 4
// 634.656 us; speedup vs baseline: 1.2581x; 1.2581x over previous
//
#include <hip/hip_runtime.h>
#include <math.h>

// ---- problem dims ----
#define BB   16
#define SS   8
#define TKK  400
#define HH   256
#define EE   128
#define VV   50000
#define OOVV 50
#define HH2  512
#define STK  (SS*TKK)     // 3200
#define NROW (BB*STK)     // 51200
#define VOO  (VV+OOVV)    // 50050
#define NVBLK 196         // ceil(50000/256)

// ---- workspace offsets (floats) ----
#define OFF_X     0        // B*E      = 2048
#define OFF_ST    2048     // B*H2     = 8192   s_t_hat = [h,c]
#define OFF_SD    10240    // B*H2     = 8192
#define OFF_WD    18432    // B*H2     = 8192
#define OFF_SCSEC 26752    // B*S      = 128 (zeroed in k_pre, atomic accum)
#define OFF_SCW   26880    // B*S*TK   = 51200 (plain stores from gemm)
#define OFF_CT    78080    // B*H2     = 8192  (zeroed in k_pre, atomic accum)
#define OFF_OUT1  86272    // B*H      = 4096
#define OFF_PGEN  90368    // B        = 16
#define OFF_VSUM  90384    // B        = 16 (zeroed in k_pre, atomic accum)
#define OFF_BT    113040   // 512*512 bf16 (512KB)

// ---- output offsets (floats) ----
#define O_FD   0
#define O_H    800800
#define O_C    804896
#define O_CT   808992
#define O_ATTN 817184
#define O_PGEN 868384
#define O_COV  868400

typedef __attribute__((ext_vector_type(8))) short bf16x8;
typedef __attribute__((ext_vector_type(4))) float f32x4;

__device__ __forceinline__ float sigm(float x){ return 1.0f/(1.0f+expf(-x)); }

__device__ __forceinline__ unsigned short f2b(float f){
  unsigned int u = __float_as_uint(f);
  unsigned int r = (u + 0x7fffu + ((u >> 16) & 1u)) >> 16;
  return (unsigned short)r;
}

__device__ __forceinline__ float wave_sum(float v){
  #pragma unroll
  for(int o=32;o>0;o>>=1) v += __shfl_xor(v,o);
  return v;
}
__device__ __forceinline__ float wave_max(float v){
  #pragma unroll
  for(int o=32;o>0;o>>=1) v = fmaxf(v,__shfl_xor(v,o));
  return v;
}

// ------------------------------------------------------------------
// k_pre: blocks 0..63  transpose Whw -> Bt bf16
//        blocks 64..71 x = [c_t_1, emb[y]] @ W_xc + b_xc
//        block  72     zero SCSEC/CT/VSUM
// grid 73 x 256
__global__ void k_pre(const float* __restrict__ Whw, unsigned short* __restrict__ Bt,
                      const int* __restrict__ y, const float* __restrict__ ct1,
                      const float* __restrict__ emb, const float* __restrict__ Wxc,
                      const float* __restrict__ bxc, float* __restrict__ ws){
  __shared__ float sm[BB*640];   // 40 KB
  int bi = blockIdx.x, tid = threadIdx.x;
  if(bi < 64){
    // transpose 64x64 tile. tile[k][n] with pad-65 rows
    float* tile = sm;
    int n0 = (bi & 7)*64, k0 = (bi >> 3)*64;
    int tx = tid & 63, ty = tid >> 6;  // ty 0..3
    #pragma unroll
    for(int it=0; it<16; it++){
      int kk = it*4 + ty;
      tile[kk*65 + tx] = Whw[(size_t)(k0+kk)*HH2 + n0 + tx];
    }
    __syncthreads();
    #pragma unroll
    for(int it=0; it<16; it++){
      int nn = it*4 + ty;
      Bt[(size_t)(n0+nn)*HH2 + k0 + tx] = f2b(tile[tx*65 + nn]);
    }
  } else if(bi < 72){
    // x projection: 16 cols for all 16 b
    for(int f=tid; f<BB*HH2; f+=256){
      int b = f >> 9, k = f & 511;
      sm[b*640 + k] = ct1[f];
    }
    for(int f=tid; f<BB*EE; f+=256){
      int b = f >> 7, e = f & 127;
      sm[b*640 + 512 + e] = emb[(size_t)y[b]*EE + e];
    }
    __syncthreads();
    int c = (bi-64)*16 + (tid & 15), b = tid >> 4;
    float acc = bxc[c];
    const float* a = &sm[b*640];
    for(int k=0;k<640;k++) acc += a[k]*Wxc[k*EE + c];
    ws[OFF_X + b*EE + c] = acc;
  } else {
    for(int f=tid; f<BB*SS; f+=256) ws[OFF_SCSEC + f] = 0.0f;
    for(int f=tid; f<BB*HH2; f+=256) ws[OFF_CT + f] = 0.0f;
    if(tid < BB) ws[OFF_VSUM + tid] = 0.0f;
  }
}

// ------------------------------------------------------------------
// fused LSTM: gates + pointwise.  grid 16 x 256 (16 j-cols x 16 b per block)
__global__ void k_lstm(const float* __restrict__ h0, const float* __restrict__ c0,
                       const float* __restrict__ Wih, const float* __restrict__ bih,
                       const float* __restrict__ Whh, const float* __restrict__ bhh,
                       float* __restrict__ ws, float* __restrict__ out){
  __shared__ float xh[BB*384];   // 24 KB  [b][ x(128) | h0(256) ]
  int tid = threadIdx.x;
  for(int f=tid; f<BB*EE; f+=256){
    int b = f >> 7, k = f & 127;
    xh[b*384 + k] = ws[OFF_X + f];
  }
  for(int f=tid; f<BB*HH; f+=256){
    int b = f >> 8, k = f & 255;
    xh[b*384 + 128 + k] = h0[f];
  }
  __syncthreads();
  int j = blockIdx.x*16 + (tid & 15), b = tid >> 4;
  float ai = bih[j      ] + bhh[j      ];
  float af = bih[j+HH   ] + bhh[j+HH   ];
  float ag = bih[j+2*HH ] + bhh[j+2*HH ];
  float ao = bih[j+3*HH ] + bhh[j+3*HH ];
  const float* a = &xh[b*384];
  for(int k=0;k<EE;k++){
    float v = a[k]; const float* w = &Wih[k*4*HH + j];
    ai += v*w[0]; af += v*w[HH]; ag += v*w[2*HH]; ao += v*w[3*HH];
  }
  const float* ah = &xh[b*384 + 128];
  for(int k=0;k<HH;k++){
    float v = ah[k]; const float* w = &Whh[k*4*HH + j];
    ai += v*w[0]; af += v*w[HH]; ag += v*w[2*HH]; ao += v*w[3*HH];
  }
  float c = sigm(af)*c0[b*HH+j] + sigm(ai)*tanhf(ag);
  float h = sigm(ao)*tanhf(c);
  out[O_H + b*HH + j] = h;
  out[O_C + b*HH + j] = c;
  ws[OFF_ST + b*HH2 + j]      = h;
  ws[OFF_ST + b*HH2 + HH + j] = c;
}

// ------------------------------------------------------------------
// sd/wd projections.  grid 64 x 256: blocks 0-31 -> SD, 32-63 -> WD (16 cols each)
__global__ void k_proj(const float* __restrict__ Wdsec, const float* __restrict__ bdsec,
                       const float* __restrict__ Wdw,  const float* __restrict__ bdw,
                       float* __restrict__ ws){
  __shared__ float st[BB*HH2];   // 32 KB
  int tid = threadIdx.x;
  for(int f=tid; f<BB*HH2; f+=256) st[f] = ws[OFF_ST + f];
  __syncthreads();
  int mi = blockIdx.x >> 5;
  int c = (blockIdx.x & 31)*16 + (tid & 15), b = tid >> 4;
  const float* Wm = mi ? Wdw : Wdsec;
  const float* bias = mi ? bdw : bdsec;
  int dst = mi ? OFF_WD : OFF_SD;
  float acc = bias[c];
  const float* a = &st[b*HH2];
  for(int k=0;k<HH2;k++) acc += a[k]*Wm[k*HH2 + c];
  ws[dst + b*HH2 + c] = acc;
}

// ------------------------------------------------------------------
// k_gemm4 (blocks 0..1599): 32 rows x all 512 cols, A LDS-resident bf16,
//   B double-buffered.  sc_w[row]=sum_n tanh(A@Whw + wd + cov*Wcw)*vw
// blocks 1600..1727: section attention (esec) -> atomicAdd SCSEC
// grid 1728 x 256, LDS 64 KB
__global__ __launch_bounds__(256) void k_gemm4(
        const float* __restrict__ A, const unsigned short* __restrict__ Bt,
        const float* __restrict__ Wcw, const float* __restrict__ vw,
        const float* __restrict__ cover,
        const float* __restrict__ sec, const float* __restrict__ Whsec,
        const float* __restrict__ vsec, float* __restrict__ ws){
  __shared__ __align__(16) unsigned short smem[32768];   // 64 KB
  int tid = threadIdx.x;
  if(blockIdx.x >= 1600){
    // ---- esec branch ----
    float* fsm = (float*)smem;          // 32 rows x 512 = 64 KB
    int bi = blockIdx.x - 1600;
    int cc = bi & 31, rc = bi >> 5;     // col chunk (16), row chunk (32 rows)
    for(int f=tid; f<32*HH2; f+=256)
      fsm[f] = sec[(size_t)rc*32*HH2 + f];
    __syncthreads();
    int c = cc*16 + (tid & 15), rp = tid >> 4;
    float vs = vsec[c];
    #pragma unroll
    for(int r2=0;r2<2;r2++){
      int row = rp*2 + r2;              // 0..31 within chunk
      int grow = rc*32 + row;           // (b*8+s)
      int b = grow >> 3;
      float acc = 0.0f;
      const float* a = &fsm[row*HH2];
      for(int k=0;k<HH2;k++) acc += a[k]*Whsec[k*HH2 + c];
      float v = tanhf(acc + ws[OFF_SD + b*HH2 + c]) * vs;
      v += __shfl_xor(v,1,16); v += __shfl_xor(v,2,16);
      v += __shfl_xor(v,4,16); v += __shfl_xor(v,8,16);
      if((tid & 15)==0) atomicAdd(&ws[OFF_SCSEC + grow], v);
    }
    return;
  }
  // ---- gemm branch ----
  unsigned short* As = smem;            // 32 rows x 512 k bf16 (swizzled)
  unsigned short* Bs = smem + 32*512;   // 2 x (128 cols x 64 k)
  int w = tid >> 6, lane = tid & 63;
  int m = lane & 15, q = lane >> 4;
  int mh = m & 7;
  int rh = w >> 1, ch = w & 1;          // row-half (16 rows), col-half (64 of 128)
  int row0 = blockIdx.x * 32;
  int b = blockIdx.x / 100;             // 100 blocks per batch
  float cov[4];
  #pragma unroll
  for(int r=0;r<4;r++) cov[r] = cover[row0 + rh*16 + q*4 + r];
  float rsum[4] = {0,0,0,0};
  f32x4 acc[4];
  #pragma unroll
  for(int j=0;j<4;j++) acc[j] = (f32x4){0.f,0.f,0.f,0.f};

  // stage A: 32 rows x 512 k, fp32 -> bf16, swizzled k-groups
  #pragma unroll
  for(int it=0; it<8; it++){
    int gi = tid + 256*it;              // 0..2047 (8-elem groups)
    int row = gi >> 6, g = gi & 63;
    const float4* src = (const float4*)&A[(size_t)(row0+row)*HH2 + g*8];
    float4 v0 = src[0], v1 = src[1];
    union{ bf16x8 v; unsigned short u[8]; } t;
    t.u[0]=f2b(v0.x); t.u[1]=f2b(v0.y); t.u[2]=f2b(v0.z); t.u[3]=f2b(v0.w);
    t.u[4]=f2b(v1.x); t.u[5]=f2b(v1.y); t.u[6]=f2b(v1.z); t.u[7]=f2b(v1.w);
    *(bf16x8*)&As[row*512 + ((g ^ (row&7))*8)] = t.v;
  }
  // stage B round 0 (cp=0, kc=0)
  #pragma unroll
  for(int p=0;p<4;p++){
    int c = tid + 256*p;                // 0..1023
    int col = c >> 3, kg = c & 7;
    bf16x8 bv = *(const bf16x8*)&Bt[(size_t)col*HH2 + kg*8];
    *(bf16x8*)&Bs[col*64 + ((kg ^ (col&7))*8)] = bv;
  }
  __syncthreads();

  bf16x8 pb[4];
  for(int r=0; r<32; r++){
    int cur = r & 1;
    int cp = r >> 3, kc = r & 7;
    if(r < 31){
      int nr = r + 1;
      int ncp = nr >> 3, nkc = nr & 7;
      #pragma unroll
      for(int p=0;p<4;p++){
        int c = tid + 256*p;
        int col = c >> 3, kg = c & 7;
        pb[p] = *(const bf16x8*)&Bt[(size_t)(ncp*128 + col)*HH2 + nkc*64 + kg*8];
      }
    }
    // compute
    #pragma unroll
    for(int kk=0; kk<2; kk++){
      int G = kc*8 + kk*4 + q;
      bf16x8 afr = *(bf16x8*)&As[(rh*16+m)*512 + ((G ^ mh)*8)];
      #pragma unroll
      for(int j=0;j<4;j++){
        int colr = ch*64 + j*16 + m;
        bf16x8 bfr = *(bf16x8*)&Bs[cur*8192 + colr*64 + (((kk*4+q) ^ mh)*8)];
        acc[j] = __builtin_amdgcn_mfma_f32_16x16x32_bf16(afr, bfr, acc[j], 0,0,0);
      }
    }
    if(r < 31){
      int nb = cur ^ 1;
      #pragma unroll
      for(int p=0;p<4;p++){
        int c = tid + 256*p;
        int col = c >> 3, kg = c & 7;
        *(bf16x8*)&Bs[nb*8192 + col*64 + ((kg ^ (col&7))*8)] = pb[p];
      }
    }
    if(kc == 7){
      // fold this 128-col chunk (this wave's 64-col half)
      #pragma unroll
      for(int j=0;j<4;j++){
        int col = cp*128 + ch*64 + j*16 + m;
        float wdv = ws[OFF_WD + b*HH2 + col];
        float wcv = Wcw[col], vwv = vw[col];
        #pragma unroll
        for(int rr=0;rr<4;rr++)
          rsum[rr] += tanhf(acc[j][rr] + wdv + cov[rr]*wcv) * vwv;
        acc[j] = (f32x4){0.f,0.f,0.f,0.f};
      }
    }
    __syncthreads();
  }
  // cross-wave row reduction (waves 2w,2w+1 share rows? no: waves with same rh)
  float* rbuf = (float*)smem;           // reuse LDS (all waves past final barrier)
  #pragma unroll
  for(int rr=0;rr<4;rr++){
    float v = rsum[rr];
    v += __shfl_xor(v,1,16); v += __shfl_xor(v,2,16);
    v += __shfl_xor(v,4,16); v += __shfl_xor(v,8,16);
    if(m==0) rbuf[w*16 + q*4 + rr] = v;
  }
  __syncthreads();
  if(tid < 32){
    int row = tid & 15, half = tid >> 4;
    // waves: rh = w>>1 -> rows half*16; pair (w=half*2, w=half*2+1)
    float v = rbuf[(half*2)*16 + row] + rbuf[(half*2+1)*16 + row];
    ws[OFF_SCW + row0 + half*16 + row] = v;
  }
}

// ------------------------------------------------------------------
// beta (inline) + attn softmax + mask + renorm + coverage out.  grid 16 x 256
__global__ void k_attn(const float* __restrict__ mask, const float* __restrict__ cover,
                       float* __restrict__ ws, float* __restrict__ out){
  int b = blockIdx.x, tid = threadIdx.x;
  __shared__ float vals[STK];
  __shared__ float red[4];
  __shared__ float sc[SS];
  if(tid < SS) sc[tid] = ws[OFF_SCSEC + b*SS + tid];
  __syncthreads();
  float bm = -1e30f;
  #pragma unroll
  for(int s=0;s<SS;s++) bm = fmaxf(bm, sc[s]);
  float be[SS]; float bsum = 0.0f;
  #pragma unroll
  for(int s=0;s<SS;s++){ be[s] = expf(sc[s]-bm); bsum += be[s]; }
  #pragma unroll
  for(int s=0;s<SS;s++) be[s] /= bsum;
  int lane = tid & 63, w = tid >> 6;
  float m = -1e30f;
  for(int j=tid;j<STK;j+=256){
    float v = be[j/TKK] * ws[OFF_SCW + b*STK + j];
    vals[j] = v; m = fmaxf(m, v);
  }
  m = wave_max(m);
  if(lane==0) red[w] = m;
  __syncthreads();
  m = fmaxf(fmaxf(red[0],red[1]), fmaxf(red[2],red[3]));
  __syncthreads();
  float ssum = 0.0f;
  for(int j=tid;j<STK;j+=256){
    float e = expf(vals[j]-m) * mask[b*STK + j];
    vals[j] = e; ssum += e;
  }
  ssum = wave_sum(ssum);
  if(lane==0) red[w] = ssum;
  __syncthreads();
  float inv = 1.0f/(red[0]+red[1]+red[2]+red[3]);
  for(int j=tid;j<STK;j+=256){
    float a = vals[j]*inv;
    out[O_ATTN + b*STK + j] = a;
    out[O_COV  + b*STK + j] = cover[b*STK + j] + a;
  }
}

// ------------------------------------------------------------------
// c_t = attn @ enc.  grid (50,16) x 256, atomic accumulate into CT
__global__ void k_ct(const float* __restrict__ enc, const float* __restrict__ out,
                     float* __restrict__ ws){
  int b = blockIdx.y, tid = threadIdx.x;
  __shared__ float a[64];
  int t0 = blockIdx.x*64;
  if(tid<64) a[tid] = out[O_ATTN + b*STK + t0 + tid];
  __syncthreads();
  float acc0=0.0f, acc1=0.0f;
  #pragma unroll 4
  for(int tt=0;tt<64;tt++){
    const float* row = &enc[(size_t)(b*STK + t0 + tt)*HH2];
    float av = a[tt];
    acc0 += av*row[tid];
    acc1 += av*row[256+tid];
  }
  atomicAdd(&ws[OFF_CT + b*HH2 + tid],       acc0);
  atomicAdd(&ws[OFF_CT + b*HH2 + 256 + tid], acc1);
}

// ------------------------------------------------------------------
// out1 + p_gen + c_t output copy.  grid 16 x 256 (16 cols x 16 b)
__global__ void k_out1(const float* __restrict__ Wp, const float* __restrict__ bp,
                       const float* __restrict__ Wo1, const float* __restrict__ bo1,
                       float* __restrict__ ws, float* __restrict__ out){
  __shared__ float cat[BB*768];   // 48 KB  [b][ h(256) | ct(512) ]
  int tid = threadIdx.x;
  for(int f=tid; f<BB*768; f+=256){
    int b = f/768, r = f - b*768;
    cat[f] = (r < HH) ? ws[OFF_ST + b*HH2 + r] : ws[OFF_CT + b*HH2 + (r-HH)];
  }
  __syncthreads();
  int c = blockIdx.x*16 + (tid & 15), b = tid >> 4;
  float acc = bo1[c];
  const float* a = &cat[b*768];
  for(int k=0;k<HH;k++)  acc += a[k]*Wo1[k*HH + c];
  for(int k=0;k<HH2;k++) acc += a[HH+k]*Wo1[(HH+k)*HH + c];
  ws[OFF_OUT1 + b*HH + c] = acc;
  // p_gen for batch = blockIdx.x (wave 0)
  if(tid < 64){
    int bb = blockIdx.x;
    float p = 0.0f;
    for(int k=tid;k<4*HH+EE;k+=64){
      float val = (k < HH2) ? ws[OFF_CT + bb*HH2 + k]
                : (k < 4*HH) ? ws[OFF_ST + bb*HH2 + (k-HH2)]
                : ws[OFF_X + bb*EE + (k-4*HH)];
      p += val * Wp[k];
    }
    p = wave_sum(p);
    if(tid==0){
      float pg = sigm(p + bp[0]);
      ws[OFF_PGEN + bb] = pg;
      out[O_PGEN + bb]  = pg;
    }
  }
  // c_t output copy for batch = blockIdx.x
  out[O_CT + blockIdx.x*HH2 + tid]       = cat[blockIdx.x*768 + HH + tid];
  out[O_CT + blockIdx.x*HH2 + 256 + tid] = cat[blockIdx.x*768 + HH + 256 + tid];
}

// ------------------------------------------------------------------
// logits -> exp (no max; logits are tiny) in final_dist area + atomic sums.
// grid 196 x 256
__global__ void k_logits(const float* __restrict__ W2, const float* __restrict__ b2,
                         float* __restrict__ ws, float* __restrict__ out){
  int tid = threadIdx.x;
  int c = blockIdx.x*256 + tid;
  __shared__ float o1[BB*HH];   // 16 KB
  __shared__ float lsum[4*BB];
  for(int i=tid;i<BB*HH;i+=256) o1[i] = ws[OFF_OUT1 + i];
  __syncthreads();
  bool ok = c < VV;
  float acc[BB] = {};
  if(ok){
    for(int k=0;k<HH;k++){
      float wv = W2[(size_t)k*VV + c];
      #pragma unroll
      for(int bb=0;bb<BB;bb++) acc[bb] += o1[bb*HH+k]*wv;
    }
  }
  float bias = ok ? b2[c] : 0.0f;
  int lane = tid & 63, w = tid >> 6;
  #pragma unroll
  for(int bb=0;bb<BB;bb++){
    float e = ok ? expf(acc[bb]+bias) : 0.0f;
    if(ok) out[(size_t)bb*VOO + c] = e;
    float sv = wave_sum(e);
    if(lane==0) lsum[w*BB+bb] = sv;
  }
  __syncthreads();
  if(tid < BB){
    float s = lsum[tid]+lsum[BB+tid]+lsum[2*BB+tid]+lsum[3*BB+tid];
    atomicAdd(&ws[OFF_VSUM + tid], s);
  }
}

// ------------------------------------------------------------------
// final_dist = p_gen * e / sum  (v < V), extra_zeros tail.  grid (196,16) x 256
__global__ void k_final(const float* __restrict__ xz, float* __restrict__ ws,
                        float* __restrict__ out){
  int b = blockIdx.y;
  int v = blockIdx.x*256 + threadIdx.x;
  float s = ws[OFF_VSUM + b];
  float pg = ws[OFF_PGEN + b];
  if(v < VV)       out[(size_t)b*VOO + v] = pg * out[(size_t)b*VOO + v] / s;
  else if(v < VOO) out[(size_t)b*VOO + v] = xz[b*OOVV + (v-VV)];
}

// ------------------------------------------------------------------
// scatter-add (1-p_gen)*attn at extend-vocab indices.  grid 16 x 256
__global__ void k_scatter(const int* __restrict__ ebev, float* __restrict__ ws,
                          float* __restrict__ out){
  int b = blockIdx.x;
  float r = 1.0f - ws[OFF_PGEN + b];
  for(int j=threadIdx.x;j<STK;j+=256){
    int idx = ebev[b*STK + j];
    atomicAdd(&out[(size_t)b*VOO + idx], r*out[O_ATTN + b*STK + j]);
  }
}

extern "C" void kernel_launch(void* const* d_in, const int* in_sizes, int n_in,
                              void* d_out, int out_size, void* d_ws, size_t ws_size,
                              hipStream_t stream){
  const int*   y     = (const int*)  d_in[0];
  const float* h0    = (const float*)d_in[1];
  const float* c0    = (const float*)d_in[2];
  const float* enc   = (const float*)d_in[3];
  const float* sec   = (const float*)d_in[4];
  const float* mask  = (const float*)d_in[5];
  const float* ct1   = (const float*)d_in[6];
  const float* xz    = (const float*)d_in[7];
  const int*   ebev  = (const int*)  d_in[8];
  const float* cover = (const float*)d_in[9];
  /* d_in[10] = gamma (unused by reference) */
  const float* emb   = (const float*)d_in[11];
  const float* Wxc   = (const float*)d_in[12];
  const float* bxc   = (const float*)d_in[13];
  const float* Wih   = (const float*)d_in[14];
  const float* bih   = (const float*)d_in[15];
  const float* Whh   = (const float*)d_in[16];
  const float* bhh   = (const float*)d_in[17];
  const float* Whsec = (const float*)d_in[18];
  const float* Wdsec = (const float*)d_in[19];
  const float* bdsec = (const float*)d_in[20];
  const float* vsec  = (const float*)d_in[21];
  const float* Whw   = (const float*)d_in[22];
  const float* Wcw   = (const float*)d_in[23];
  const float* Wdw   = (const float*)d_in[24];
  const float* bdw   = (const float*)d_in[25];
  const float* vw    = (const float*)d_in[26];
  const float* Wp    = (const float*)d_in[27];
  const float* bp    = (const float*)d_in[28];
  const float* Wo1   = (const float*)d_in[29];
  const float* bo1   = (const float*)d_in[30];
  const float* Wo2   = (const float*)d_in[31];
  const float* bo2   = (const float*)d_in[32];
  float* out = (float*)d_out;
  float* ws  = (float*)d_ws;
  unsigned short* Bt = (unsigned short*)(ws + OFF_BT);

  k_pre    <<<dim3(73),       dim3(256), 0, stream>>>(Whw, Bt, y, ct1, emb, Wxc, bxc, ws);
  k_lstm   <<<dim3(16),       dim3(256), 0, stream>>>(h0, c0, Wih, bih, Whh, bhh, ws, out);
  k_proj   <<<dim3(64),       dim3(256), 0, stream>>>(Wdsec, bdsec, Wdw, bdw, ws);
  k_gemm4  <<<dim3(1728),     dim3(256), 0, stream>>>(enc, Bt, Wcw, vw, cover, sec, Whsec, vsec, ws);
  k_attn   <<<dim3(BB),       dim3(256), 0, stream>>>(mask, cover, ws, out);
  k_ct     <<<dim3(50,BB),    dim3(256), 0, stream>>>(enc, out, ws);
  k_out1   <<<dim3(16),       dim3(256), 0, stream>>>(Wp, bp, Wo1, bo1, ws, out);
  k_logits <<<dim3(NVBLK),    dim3(256), 0, stream>>>(Wo2, bo2, ws, out);
  k_final  <<<dim3(NVBLK,BB), dim3(256), 0, stream>>>(xz, ws, out);
  k_scatter<<<dim3(BB),       dim3(256), 0, stream>>>(ebev, ws, out);
}

// Round 5
// 627.389 us; speedup vs baseline: 1.2727x; 1.0116x over previous
//
#include <hip/hip_runtime.h>
#include <math.h>

// ---- problem dims ----
#define BB   16
#define SS   8
#define TKK  400
#define HH   256
#define EE   128
#define VV   50000
#define OOVV 50
#define HH2  512
#define STK  (SS*TKK)     // 3200
#define VOO  (VV+OOVV)    // 50050

// ---- workspace offsets (floats) ----
#define OFF_X     0        // B*E      = 2048
#define OFF_ST    2048     // B*H2     = 8192   s_t_hat = [h,c]
#define OFF_SD    10240    // B*H2     = 8192
#define OFF_WD    18432    // B*H2     = 8192
#define OFF_SCSEC 26752    // B*S      = 128 (zeroed in k_pre, atomic accum)
#define OFF_SCW   26880    // B*S*TK   = 51200 (plain stores from gemm)
#define OFF_CT    78080    // B*H2     = 8192  (zeroed in k_pre, atomic accum)
#define OFF_OUT1  86272    // B*H      = 4096
#define OFF_PGEN  90368    // B        = 16
#define OFF_PSUM  93520    // 782*16   = 12512 (plain stores)
#define OFF_BT    113040   // 512*512 bf16 (512KB), layout [k>>3][col][8]

// ---- output offsets (floats) ----
#define O_FD   0
#define O_H    800800
#define O_C    804896
#define O_CT   808992
#define O_ATTN 817184
#define O_PGEN 868384
#define O_COV  868400

#define NLBLK 782          // logits blocks (64 cols each)

typedef __attribute__((ext_vector_type(8))) short bf16x8;
typedef __attribute__((ext_vector_type(4))) float f32x4;

__device__ __forceinline__ float sigm(float x){ return 1.0f/(1.0f+expf(-x)); }

__device__ __forceinline__ unsigned short f2b(float f){
  unsigned int u = __float_as_uint(f);
  unsigned int r = (u + 0x7fffu + ((u >> 16) & 1u)) >> 16;
  return (unsigned short)r;
}

__device__ __forceinline__ float wave_sum(float v){
  #pragma unroll
  for(int o=32;o>0;o>>=1) v += __shfl_xor(v,o);
  return v;
}
__device__ __forceinline__ float wave_max(float v){
  #pragma unroll
  for(int o=32;o>0;o>>=1) v = fmaxf(v,__shfl_xor(v,o));
  return v;
}

// ------------------------------------------------------------------
// k_pre: blocks 0..63  transpose Whw -> Btg bf16, layout [k>>3][col][8]
//        blocks 64..79 x = [c_t_1, emb[y]] @ W_xc + b_xc (8 cols/block, ksplit 2)
//        block  80     zero SCSEC/CT
// grid 81 x 256
__global__ void k_pre(const float* __restrict__ Whw, unsigned short* __restrict__ Btg,
                      const int* __restrict__ y, const float* __restrict__ ct1,
                      const float* __restrict__ emb, const float* __restrict__ Wxc,
                      const float* __restrict__ bxc, float* __restrict__ ws){
  __shared__ float sm[10440];
  int bi = blockIdx.x, tid = threadIdx.x;
  if(bi < 64){
    // load 64x64 tile of Whw [k][n] into LDS (pad 65)
    int n0 = (bi & 7)*64, k0 = (bi >> 3)*64;
    int tx = tid & 63, ty = tid >> 6;  // ty 0..3
    #pragma unroll
    for(int it=0; it<16; it++){
      int kk = it*4 + ty;
      sm[kk*65 + tx] = Whw[(size_t)(k0+kk)*HH2 + n0 + tx];
    }
    __syncthreads();
    // write Btg[kgG][col][8]
    #pragma unroll
    for(int it=0; it<2; it++){
      int kgl = it*4 + ty;            // 0..7
      int kgG = (k0 >> 3) + kgl;
      union{ bf16x8 v; unsigned short u[8]; } t;
      #pragma unroll
      for(int j=0;j<8;j++) t.u[j] = f2b(sm[(kgl*8+j)*65 + tx]);
      *(bf16x8*)&Btg[((size_t)kgG*HH2 + n0 + tx)*8] = t.v;
    }
  } else if(bi < 80){
    // x projection: 8 cols per block, k split 2
    float* cat = sm;                  // [b][640]
    float* red = sm + 10240;          // 128
    for(int f=tid; f<BB*640; f+=256){
      int b = f/640, r = f - b*640;
      cat[f] = (r < HH2) ? ct1[b*HH2 + r] : emb[(size_t)y[b]*EE + (r-HH2)];
    }
    __syncthreads();
    int c = (bi-64)*8 + (tid & 7);
    int b = (tid >> 3) & 15;
    int kh = tid >> 7;                // 0..1
    float acc = 0.0f;
    const float* a = &cat[b*640];
    for(int k=kh*320; k<kh*320+320; k++) acc += a[k]*Wxc[k*EE + c];
    if(kh==1) red[b*8 + (tid&7)] = acc;
    __syncthreads();
    if(kh==0) ws[OFF_X + b*EE + c] = acc + red[b*8 + (tid&7)] + bxc[c];
  } else {
    for(int f=tid; f<BB*SS; f+=256) ws[OFF_SCSEC + f] = 0.0f;
    for(int f=tid; f<BB*HH2; f+=256) ws[OFF_CT + f] = 0.0f;
  }
}

// ------------------------------------------------------------------
// fused LSTM, k split 4.  grid 16 x 1024  (16 j-cols x 16 b x 4 kq)
__global__ void k_lstm(const float* __restrict__ h0, const float* __restrict__ c0,
                       const float* __restrict__ Wih, const float* __restrict__ bih,
                       const float* __restrict__ Whh, const float* __restrict__ bhh,
                       float* __restrict__ ws, float* __restrict__ out){
  __shared__ float xh[BB*384];        // 24 KB  [b][ x(128) | h0(256) ]
  __shared__ float red[3*256*4];      // 12 KB
  int tid = threadIdx.x;
  for(int f=tid; f<BB*EE; f+=1024){
    int b = f >> 7, k = f & 127;
    xh[b*384 + k] = ws[OFF_X + f];
  }
  for(int f=tid; f<BB*HH; f+=1024){
    int b = f >> 8, k = f & 255;
    xh[b*384 + 128 + k] = h0[f];
  }
  __syncthreads();
  int jl = tid & 15, b = (tid >> 4) & 15, kq = tid >> 8;
  int j = blockIdx.x*16 + jl;
  float a0=0.f, a1=0.f, a2=0.f, a3=0.f;
  const float* a = &xh[b*384];
  for(int k=kq*96; k<kq*96+96; k++){
    float v = a[k];
    const float* w = (k < EE) ? &Wih[k*4*HH + j] : &Whh[(k-EE)*4*HH + j];
    a0 += v*w[0]; a1 += v*w[HH]; a2 += v*w[2*HH]; a3 += v*w[3*HH];
  }
  if(kq){
    float* r = &red[((kq-1)*256 + b*16 + jl)*4];
    r[0]=a0; r[1]=a1; r[2]=a2; r[3]=a3;
  }
  __syncthreads();
  if(kq==0){
    #pragma unroll
    for(int p=0;p<3;p++){
      const float* r = &red[(p*256 + b*16 + jl)*4];
      a0+=r[0]; a1+=r[1]; a2+=r[2]; a3+=r[3];
    }
    a0 += bih[j] + bhh[j];
    a1 += bih[j+HH] + bhh[j+HH];
    a2 += bih[j+2*HH] + bhh[j+2*HH];
    a3 += bih[j+3*HH] + bhh[j+3*HH];
    float c = sigm(a1)*c0[b*HH+j] + sigm(a0)*tanhf(a2);
    float h = sigm(a3)*tanhf(c);
    out[O_H + b*HH + j] = h;
    out[O_C + b*HH + j] = c;
    ws[OFF_ST + b*HH2 + j]      = h;
    ws[OFF_ST + b*HH2 + HH + j] = c;
  }
}

// ------------------------------------------------------------------
// sd/wd projections, k split 2.  grid 64 x 512: blocks 0-31 SD, 32-63 WD
__global__ void k_proj(const float* __restrict__ Wdsec, const float* __restrict__ bdsec,
                       const float* __restrict__ Wdw,  const float* __restrict__ bdw,
                       float* __restrict__ ws){
  __shared__ float st[BB*HH2];   // 32 KB
  __shared__ float red[256];
  int tid = threadIdx.x;
  for(int f=tid; f<BB*HH2; f+=512) st[f] = ws[OFF_ST + f];
  __syncthreads();
  int mi = blockIdx.x >> 5;
  int c = (blockIdx.x & 31)*16 + (tid & 15);
  int b = (tid >> 4) & 15;
  int kq = tid >> 8;   // 0..1
  const float* Wm = mi ? Wdw : Wdsec;
  const float* bias = mi ? bdw : bdsec;
  int dst = mi ? OFF_WD : OFF_SD;
  float acc = 0.0f;
  const float* a = &st[b*HH2];
  for(int k=kq*256; k<kq*256+256; k++) acc += a[k]*Wm[k*HH2 + c];
  if(kq==1) red[b*16 + (tid&15)] = acc;
  __syncthreads();
  if(kq==0) ws[dst + b*HH2 + c] = acc + red[b*16 + (tid&15)] + bias[c];
}

// ------------------------------------------------------------------
// k_gemm5 blocks 0..399: 128 rows x 512 cols, K=512. 512 thr, 48 KB LDS.
//   A (fp32->bf16) dbuf 2x8KB, B dbuf 2x16KB, conflict-free [kg][row/col][8].
//   sc_w[row] = sum_n tanh(A@Whw + wd[b,n] + cov[row]*Wcw[n]) * vw[n]
// blocks 400..911: section attention (k split 4) -> atomicAdd SCSEC
__global__ __launch_bounds__(512, 2) void k_gemm5(
        const float* __restrict__ A, const unsigned short* __restrict__ Btg,
        const float* __restrict__ Wcw, const float* __restrict__ vw,
        const float* __restrict__ cover,
        const float* __restrict__ sec, const float* __restrict__ Whsec,
        const float* __restrict__ vsec, float* __restrict__ ws){
  __shared__ __align__(16) unsigned short smem[24576];   // 48 KB
  int tid = threadIdx.x;
  if(blockIdx.x >= 400){
    // ---- esec: rows (b*8+s), e = tanh(sec@Whsec + sd) @ vsec ----
    float* fsm = (float*)smem;            // [16 rows][516 pad]
    float* red1 = fsm + 16*516;           // 512
    float* red2 = red1 + 512;             // 128
    int bi2 = blockIdx.x - 400;
    int rc = bi2 >> 6, cc = bi2 & 63;
    for(int f=tid; f<16*HH2; f+=512){
      int row = f >> 9, k = f & 511;
      fsm[row*516 + k] = sec[(size_t)(rc*16+row)*HH2 + k];
    }
    __syncthreads();
    int r = tid & 15, c = (tid >> 4) & 7, kq = tid >> 7;
    int col = cc*8 + c;
    float acc = 0.0f;
    const float* a = &fsm[r*516];
    for(int k=kq*128; k<kq*128+128; k++) acc += a[k]*Whsec[k*HH2 + col];
    red1[tid & 511] = acc;   // tid<512
    __syncthreads();
    if(kq==0){
      int rowg = rc*16 + r, b = rowg >> 3;
      float tot = red1[tid] + red1[tid+128] + red1[tid+256] + red1[tid+384];
      float val = tanhf(tot + ws[OFF_SD + b*HH2 + col]) * vsec[col];
      red2[tid] = val;       // tid<128 : r + c*16
    }
    __syncthreads();
    if(tid < 16){
      float s = 0.0f;
      #pragma unroll
      for(int cc2=0;cc2<8;cc2++) s += red2[tid + cc2*16];
      atomicAdd(&ws[OFF_SCSEC + rc*16 + tid], s);
    }
    return;
  }
  // ---- gemm ----
  unsigned short* As = smem;              // [2][4096]  (kg*128+row)*8
  unsigned short* Bs = smem + 8192;       // [2][8192]  (kg*256+col)*8
  int w = tid >> 6, lane = tid & 63;
  int m = lane & 15, q = lane >> 4;
  int rg = w >> 1, cg = w & 1;            // 4 row-groups x 2 col-groups
  int row0 = blockIdx.x * 128;
  int b = blockIdx.x / 25;                // 25 blocks per batch
  float cov[2][4];
  #pragma unroll
  for(int fi=0;fi<2;fi++)
    #pragma unroll
    for(int r=0;r<4;r++) cov[fi][r] = cover[row0 + rg*32 + fi*16 + q*4 + r];
  f32x4 acc[2][2][8];
  #pragma unroll
  for(int ch=0;ch<2;ch++)
    #pragma unroll
    for(int fi=0;fi<2;fi++)
      #pragma unroll
      for(int fj=0;fj<8;fj++) acc[ch][fi][fj] = (f32x4){0.f,0.f,0.f,0.f};

  int ar = tid >> 2, akg = tid & 3;       // A staging: row, kgroup
  int u0 = (tid >> 6)*128 + (tid & 63);   // B staging unit ids
  int u1 = u0 + 64;

  // prologue: stage A(kc=0) and B(step 0)
  {
    const float4* ap = (const float4*)&A[(size_t)(row0+ar)*HH2 + akg*8];
    float4 v0 = ap[0], v1 = ap[1];
    union{ bf16x8 v; unsigned short u[8]; } t;
    t.u[0]=f2b(v0.x); t.u[1]=f2b(v0.y); t.u[2]=f2b(v0.z); t.u[3]=f2b(v0.w);
    t.u[4]=f2b(v1.x); t.u[5]=f2b(v1.y); t.u[6]=f2b(v1.z); t.u[7]=f2b(v1.w);
    *(bf16x8*)&As[(akg*128 + ar)*8] = t.v;
    bf16x8 b0 = *(const bf16x8*)&Btg[((size_t)(u0>>8)*HH2 + (u0&255))*8];
    bf16x8 b1 = *(const bf16x8*)&Btg[((size_t)(u1>>8)*HH2 + (u1&255))*8];
    *(bf16x8*)&Bs[u0*8] = b0;
    *(bf16x8*)&Bs[u1*8] = b1;
  }
  __syncthreads();

  for(int kc=0; kc<16; kc++){
    #pragma unroll
    for(int ch=0; ch<2; ch++){
      int s = kc*2 + ch;
      int cs = s & 1, nxt = cs ^ 1;
      bf16x8 pb0, pb1;
      bool haveB = (s < 31);
      if(haveB){
        int sn = s + 1, kcN = sn >> 1, chN = sn & 1;
        pb0 = *(const bf16x8*)&Btg[((size_t)((kcN*4 + (u0>>8))*HH2) + chN*256 + (u0&255))*8];
        pb1 = *(const bf16x8*)&Btg[((size_t)((kcN*4 + (u1>>8))*HH2) + chN*256 + (u1&255))*8];
      }
      float4 av0, av1;
      bool haveA = (ch==0 && kc<15);
      if(haveA){
        const float4* ap = (const float4*)&A[(size_t)(row0+ar)*HH2 + (kc+1)*32 + akg*8];
        av0 = ap[0]; av1 = ap[1];
      }
      // compute on As[kc&1], Bs[cs]
      unsigned short* Ab = &As[(kc&1)*4096];
      unsigned short* Bb = &Bs[cs*8192];
      bf16x8 afr[2];
      #pragma unroll
      for(int fi=0;fi<2;fi++)
        afr[fi] = *(bf16x8*)&Ab[(q*128 + rg*32 + fi*16 + m)*8];
      #pragma unroll
      for(int fj=0;fj<8;fj++){
        bf16x8 bfr = *(bf16x8*)&Bb[(q*256 + cg*128 + fj*16 + m)*8];
        #pragma unroll
        for(int fi=0;fi<2;fi++)
          acc[ch][fi][fj] = __builtin_amdgcn_mfma_f32_16x16x32_bf16(afr[fi], bfr, acc[ch][fi][fj], 0,0,0);
      }
      if(haveB){
        *(bf16x8*)&Bs[nxt*8192 + u0*8] = pb0;
        *(bf16x8*)&Bs[nxt*8192 + u1*8] = pb1;
      }
      if(haveA){
        union{ bf16x8 v; unsigned short u[8]; } t;
        t.u[0]=f2b(av0.x); t.u[1]=f2b(av0.y); t.u[2]=f2b(av0.z); t.u[3]=f2b(av0.w);
        t.u[4]=f2b(av1.x); t.u[5]=f2b(av1.y); t.u[6]=f2b(av1.z); t.u[7]=f2b(av1.w);
        *(bf16x8*)&As[((kc+1)&1)*4096 + (akg*128 + ar)*8] = t.v;
      }
      __syncthreads();
    }
  }
  // epilogue: fold cols -> per-row sums
  float rsum[2][4] = {{0,0,0,0},{0,0,0,0}};
  #pragma unroll
  for(int ch=0;ch<2;ch++)
    #pragma unroll
    for(int fj=0;fj<8;fj++){
      int col = ch*256 + cg*128 + fj*16 + m;
      float wdv = ws[OFF_WD + b*HH2 + col];
      float wcv = Wcw[col], vwv = vw[col];
      #pragma unroll
      for(int fi=0;fi<2;fi++)
        #pragma unroll
        for(int r=0;r<4;r++)
          rsum[fi][r] += tanhf(acc[ch][fi][fj][r] + wdv + cov[fi][r]*wcv) * vwv;
    }
  float* rbuf = (float*)smem;   // 256 floats (all LDS reads done pre-barrier)
  #pragma unroll
  for(int fi=0;fi<2;fi++)
    #pragma unroll
    for(int r=0;r<4;r++){
      float v = rsum[fi][r];
      v += __shfl_xor(v,1,16); v += __shfl_xor(v,2,16);
      v += __shfl_xor(v,4,16); v += __shfl_xor(v,8,16);
      if(m==0) rbuf[cg*128 + rg*32 + fi*16 + q*4 + r] = v;
    }
  __syncthreads();
  if(tid < 128) ws[OFF_SCW + row0 + tid] = rbuf[tid] + rbuf[128 + tid];
}

// ------------------------------------------------------------------
// beta (inline) + attn softmax + mask + renorm + coverage out.  grid 16 x 256
__global__ void k_attn(const float* __restrict__ mask, const float* __restrict__ cover,
                       float* __restrict__ ws, float* __restrict__ out){
  int b = blockIdx.x, tid = threadIdx.x;
  __shared__ float vals[STK];
  __shared__ float red[4];
  __shared__ float sc[SS];
  if(tid < SS) sc[tid] = ws[OFF_SCSEC + b*SS + tid];
  __syncthreads();
  float bm = -1e30f;
  #pragma unroll
  for(int s=0;s<SS;s++) bm = fmaxf(bm, sc[s]);
  float be[SS]; float bsum = 0.0f;
  #pragma unroll
  for(int s=0;s<SS;s++){ be[s] = expf(sc[s]-bm); bsum += be[s]; }
  #pragma unroll
  for(int s=0;s<SS;s++) be[s] /= bsum;
  int lane = tid & 63, w = tid >> 6;
  float m = -1e30f;
  for(int j=tid;j<STK;j+=256){
    float v = be[j/TKK] * ws[OFF_SCW + b*STK + j];
    vals[j] = v; m = fmaxf(m, v);
  }
  m = wave_max(m);
  if(lane==0) red[w] = m;
  __syncthreads();
  m = fmaxf(fmaxf(red[0],red[1]), fmaxf(red[2],red[3]));
  __syncthreads();
  float ssum = 0.0f;
  for(int j=tid;j<STK;j+=256){
    float e = expf(vals[j]-m) * mask[b*STK + j];
    vals[j] = e; ssum += e;
  }
  ssum = wave_sum(ssum);
  if(lane==0) red[w] = ssum;
  __syncthreads();
  float inv = 1.0f/(red[0]+red[1]+red[2]+red[3]);
  for(int j=tid;j<STK;j+=256){
    float a = vals[j]*inv;
    out[O_ATTN + b*STK + j] = a;
    out[O_COV  + b*STK + j] = cover[b*STK + j] + a;
  }
}

// ------------------------------------------------------------------
// c_t = attn @ enc.  grid (50,16) x 256, atomic accumulate into CT
__global__ void k_ct(const float* __restrict__ enc, const float* __restrict__ out,
                     float* __restrict__ ws){
  int b = blockIdx.y, tid = threadIdx.x;
  __shared__ float a[64];
  int t0 = blockIdx.x*64;
  if(tid<64) a[tid] = out[O_ATTN + b*STK + t0 + tid];
  __syncthreads();
  float acc0=0.0f, acc1=0.0f;
  #pragma unroll 4
  for(int tt=0;tt<64;tt++){
    const float* row = &enc[(size_t)(b*STK + t0 + tt)*HH2];
    float av = a[tt];
    acc0 += av*row[tid];
    acc1 += av*row[256+tid];
  }
  atomicAdd(&ws[OFF_CT + b*HH2 + tid],       acc0);
  atomicAdd(&ws[OFF_CT + b*HH2 + 256 + tid], acc1);
}

// ------------------------------------------------------------------
// out1 (k split 4) + p_gen + c_t output copy.  grid 17 x 1024
__global__ void k_out1(const float* __restrict__ Wp, const float* __restrict__ bp,
                       const float* __restrict__ Wo1, const float* __restrict__ bo1,
                       float* __restrict__ ws, float* __restrict__ out){
  __shared__ float cat[BB*768];   // 48 KB  [b][ h(256) | ct(512) ]
  __shared__ float red[3*256];
  int tid = threadIdx.x;
  if(blockIdx.x == 16){
    // p_gen: wave per b
    int b = tid >> 6, lane = tid & 63;
    float p = 0.0f;
    for(int k=lane;k<4*HH+EE;k+=64){
      float val = (k < HH2) ? ws[OFF_CT + b*HH2 + k]
                : (k < 4*HH) ? ws[OFF_ST + b*HH2 + (k-HH2)]
                : ws[OFF_X + b*EE + (k-4*HH)];
      p += val * Wp[k];
    }
    p = wave_sum(p);
    if(lane==0){
      float pg = sigm(p + bp[0]);
      ws[OFF_PGEN + b] = pg;
      out[O_PGEN + b]  = pg;
    }
    for(int f=tid; f<BB*HH2; f+=1024) out[O_CT + f] = ws[OFF_CT + f];
    return;
  }
  for(int f=tid; f<BB*768; f+=1024){
    int b = f/768, r = f - b*768;
    cat[f] = (r < HH) ? ws[OFF_ST + b*HH2 + r] : ws[OFF_CT + b*HH2 + (r-HH)];
  }
  __syncthreads();
  int c = blockIdx.x*16 + (tid & 15);
  int b = (tid >> 4) & 15;
  int kq = tid >> 8;
  float acc = 0.0f;
  const float* a = &cat[b*768];
  for(int k=kq*192; k<kq*192+192; k++) acc += a[k]*Wo1[k*HH + c];
  if(kq) red[(kq-1)*256 + b*16 + (tid&15)] = acc;
  __syncthreads();
  if(kq==0){
    acc += red[b*16+(tid&15)] + red[256 + b*16+(tid&15)] + red[512 + b*16+(tid&15)];
    ws[OFF_OUT1 + b*HH + c] = acc + bo1[c];
  }
}

// ------------------------------------------------------------------
// logits -> exp (logits tiny, no max needed) + per-block PSUM.  grid 782 x 256
__global__ void k_logits(const float* __restrict__ W2, const float* __restrict__ b2,
                         float* __restrict__ ws, float* __restrict__ out){
  int tid = threadIdx.x;
  int c = blockIdx.x*64 + (tid & 63);
  int bq = tid >> 6;                 // 0..3 -> b = bq*4..bq*4+3
  __shared__ float o1[BB*HH];        // 16 KB
  for(int i=tid;i<BB*HH;i+=256) o1[i] = ws[OFF_OUT1 + i];
  __syncthreads();
  bool ok = c < VV;
  float acc[4] = {0,0,0,0};
  if(ok){
    for(int k=0;k<HH;k++){
      float wv = W2[(size_t)k*VV + c];
      #pragma unroll
      for(int i=0;i<4;i++) acc[i] += o1[(bq*4+i)*HH + k]*wv;
    }
  }
  float bias = ok ? b2[c] : 0.0f;
  int lane = tid & 63;
  #pragma unroll
  for(int i=0;i<4;i++){
    float e = ok ? expf(acc[i]+bias) : 0.0f;
    if(ok) out[(size_t)(bq*4+i)*VOO + c] = e;
    float sv = wave_sum(e);
    if(lane==0) ws[OFF_PSUM + blockIdx.x*BB + bq*4 + i] = sv;
  }
}

// ------------------------------------------------------------------
// final_dist = p_gen * e / sum (v<V), extra_zeros tail.  grid (196,16) x 256
__global__ void k_final(const float* __restrict__ xz, float* __restrict__ ws,
                        float* __restrict__ out){
  int b = blockIdx.y;
  int v = blockIdx.x*256 + threadIdx.x;
  __shared__ float red[4];
  int lane = threadIdx.x & 63, w = threadIdx.x >> 6;
  float p = 0.0f;
  for(int i=threadIdx.x;i<NLBLK;i+=256) p += ws[OFF_PSUM + i*BB + b];
  p = wave_sum(p);
  if(lane==0) red[w] = p;
  __syncthreads();
  float s = red[0]+red[1]+red[2]+red[3];
  float pg = ws[OFF_PGEN + b];
  if(v < VV)       out[(size_t)b*VOO + v] = pg * out[(size_t)b*VOO + v] / s;
  else if(v < VOO) out[(size_t)b*VOO + v] = xz[b*OOVV + (v-VV)];
}

// ------------------------------------------------------------------
// scatter-add (1-p_gen)*attn at extend-vocab indices.  grid 16 x 256
__global__ void k_scatter(const int* __restrict__ ebev, float* __restrict__ ws,
                          float* __restrict__ out){
  int b = blockIdx.x;
  float r = 1.0f - ws[OFF_PGEN + b];
  for(int j=threadIdx.x;j<STK;j+=256){
    int idx = ebev[b*STK + j];
    atomicAdd(&out[(size_t)b*VOO + idx], r*out[O_ATTN + b*STK + j]);
  }
}

extern "C" void kernel_launch(void* const* d_in, const int* in_sizes, int n_in,
                              void* d_out, int out_size, void* d_ws, size_t ws_size,
                              hipStream_t stream){
  const int*   y     = (const int*)  d_in[0];
  const float* h0    = (const float*)d_in[1];
  const float* c0    = (const float*)d_in[2];
  const float* enc   = (const float*)d_in[3];
  const float* sec   = (const float*)d_in[4];
  const float* mask  = (const float*)d_in[5];
  const float* ct1   = (const float*)d_in[6];
  const float* xz    = (const float*)d_in[7];
  const int*   ebev  = (const int*)  d_in[8];
  const float* cover = (const float*)d_in[9];
  /* d_in[10] = gamma (unused by reference) */
  const float* emb   = (const float*)d_in[11];
  const float* Wxc   = (const float*)d_in[12];
  const float* bxc   = (const float*)d_in[13];
  const float* Wih   = (const float*)d_in[14];
  const float* bih   = (const float*)d_in[15];
  const float* Whh   = (const float*)d_in[16];
  const float* bhh   = (const float*)d_in[17];
  const float* Whsec = (const float*)d_in[18];
  const float* Wdsec = (const float*)d_in[19];
  const float* bdsec = (const float*)d_in[20];
  const float* vsec  = (const float*)d_in[21];
  const float* Whw   = (const float*)d_in[22];
  const float* Wcw   = (const float*)d_in[23];
  const float* Wdw   = (const float*)d_in[24];
  const float* bdw   = (const float*)d_in[25];
  const float* vw    = (const float*)d_in[26];
  const float* Wp    = (const float*)d_in[27];
  const float* bp    = (const float*)d_in[28];
  const float* Wo1   = (const float*)d_in[29];
  const float* bo1   = (const float*)d_in[30];
  const float* Wo2   = (const float*)d_in[31];
  const float* bo2   = (const float*)d_in[32];
  float* out = (float*)d_out;
  float* ws  = (float*)d_ws;
  unsigned short* Btg = (unsigned short*)(ws + OFF_BT);

  k_pre    <<<dim3(81),       dim3(256),  0, stream>>>(Whw, Btg, y, ct1, emb, Wxc, bxc, ws);
  k_lstm   <<<dim3(16),       dim3(1024), 0, stream>>>(h0, c0, Wih, bih, Whh, bhh, ws, out);
  k_proj   <<<dim3(64),       dim3(512),  0, stream>>>(Wdsec, bdsec, Wdw, bdw, ws);
  k_gemm5  <<<dim3(912),      dim3(512),  0, stream>>>(enc, Btg, Wcw, vw, cover, sec, Whsec, vsec, ws);
  k_attn   <<<dim3(BB),       dim3(256),  0, stream>>>(mask, cover, ws, out);
  k_ct     <<<dim3(50,BB),    dim3(256),  0, stream>>>(enc, out, ws);
  k_out1   <<<dim3(17),       dim3(1024), 0, stream>>>(Wp, bp, Wo1, bo1, ws, out);
  k_logits <<<dim3(NLBLK),    dim3(256),  0, stream>>>(Wo2, bo2, ws, out);
  k_final  <<<dim3(196,BB),   dim3(256),  0, stream>>>(xz, ws, out);
  k_scatter<<<dim3(BB),       dim3(256),  0, stream>>>(ebev, ws, out);
}

// Round 6
// 496.467 us; speedup vs baseline: 1.6083x; 1.2637x over previous
//
#include <hip/hip_runtime.h>
#include <math.h>

// ---- problem dims ----
#define BB   16
#define SS   8
#define TKK  400
#define HH   256
#define EE   128
#define VV   50000
#define OOVV 50
#define HH2  512
#define STK  (SS*TKK)     // 3200
#define VOO  (VV+OOVV)    // 50050

// ---- workspace offsets (floats) ----
#define OFF_X     0        // B*E      = 2048
#define OFF_ST    2048     // B*H2     = 8192   s_t_hat = [h,c]
#define OFF_SD    10240    // B*H2     = 8192
#define OFF_WD    18432    // B*H2     = 8192
#define OFF_SCSEC 26752    // B*S      = 128 (plain stores from esec branch)
#define OFF_SCW   26880    // B*S*TK   = 51200 (plain stores from gemm)
#define OFF_CT    78080    // B*H2     = 8192  (zeroed in k_pre, atomic accum)
#define OFF_OUT1  86272    // B*H      = 4096
#define OFF_PGEN  90368    // B        = 16
#define OFF_PSUM  93520    // 782*16   = 12512 (plain stores)
#define OFF_BT    113040   // 512*512 bf16 (512KB), layout [k>>3][col][8]

// ---- output offsets (floats) ----
#define O_FD   0
#define O_H    800800
#define O_C    804896
#define O_CT   808992
#define O_ATTN 817184
#define O_PGEN 868384
#define O_COV  868400

#define NLBLK 782          // logits blocks (64 cols each)
#define GEMM_NB 800

typedef __attribute__((ext_vector_type(8))) short bf16x8;
typedef __attribute__((ext_vector_type(4))) float f32x4;

__device__ __forceinline__ float sigm(float x){ return 1.0f/(1.0f+expf(-x)); }

__device__ __forceinline__ unsigned short f2b(float f){
  unsigned int u = __float_as_uint(f);
  unsigned int r = (u + 0x7fffu + ((u >> 16) & 1u)) >> 16;
  return (unsigned short)r;
}

__device__ __forceinline__ float wave_sum(float v){
  #pragma unroll
  for(int o=32;o>0;o>>=1) v += __shfl_xor(v,o);
  return v;
}
__device__ __forceinline__ float wave_max(float v){
  #pragma unroll
  for(int o=32;o>0;o>>=1) v = fmaxf(v,__shfl_xor(v,o));
  return v;
}

// ------------------------------------------------------------------
// k_pre: blocks 0..63  transpose Whw -> Btg bf16, layout [k>>3][col][8]
//        blocks 64..79 x = [c_t_1, emb[y]] @ W_xc + b_xc (8 cols/block, ksplit 2)
//        block  80     zero CT
// grid 81 x 256
__global__ void k_pre(const float* __restrict__ Whw, unsigned short* __restrict__ Btg,
                      const int* __restrict__ y, const float* __restrict__ ct1,
                      const float* __restrict__ emb, const float* __restrict__ Wxc,
                      const float* __restrict__ bxc, float* __restrict__ ws){
  __shared__ float sm[10440];
  int bi = blockIdx.x, tid = threadIdx.x;
  if(bi < 64){
    // load 64x64 tile of Whw [k][n] into LDS (pad 65)
    int n0 = (bi & 7)*64, k0 = (bi >> 3)*64;
    int tx = tid & 63, ty = tid >> 6;  // ty 0..3
    #pragma unroll
    for(int it=0; it<16; it++){
      int kk = it*4 + ty;
      sm[kk*65 + tx] = Whw[(size_t)(k0+kk)*HH2 + n0 + tx];
    }
    __syncthreads();
    // write Btg[kgG][col][8]
    #pragma unroll
    for(int it=0; it<2; it++){
      int kgl = it*4 + ty;            // 0..7
      int kgG = (k0 >> 3) + kgl;
      union{ bf16x8 v; unsigned short u[8]; } t;
      #pragma unroll
      for(int j=0;j<8;j++) t.u[j] = f2b(sm[(kgl*8+j)*65 + tx]);
      *(bf16x8*)&Btg[((size_t)kgG*HH2 + n0 + tx)*8] = t.v;
    }
  } else if(bi < 80){
    // x projection: 8 cols per block, k split 2
    float* cat = sm;                  // [b][640]
    float* red = sm + 10240;          // 128
    for(int f=tid; f<BB*640; f+=256){
      int b = f/640, r = f - b*640;
      cat[f] = (r < HH2) ? ct1[b*HH2 + r] : emb[(size_t)y[b]*EE + (r-HH2)];
    }
    __syncthreads();
    int c = (bi-64)*8 + (tid & 7);
    int b = (tid >> 3) & 15;
    int kh = tid >> 7;                // 0..1
    float acc = 0.0f;
    const float* a = &cat[b*640];
    for(int k=kh*320; k<kh*320+320; k++) acc += a[k]*Wxc[k*EE + c];
    if(kh==1) red[b*8 + (tid&7)] = acc;
    __syncthreads();
    if(kh==0) ws[OFF_X + b*EE + c] = acc + red[b*8 + (tid&7)] + bxc[c];
  } else {
    for(int f=tid; f<BB*HH2; f+=256) ws[OFF_CT + f] = 0.0f;
  }
}

// ------------------------------------------------------------------
// fused LSTM.  grid 64 x 256: block = 16 j-cols x 4 b, ksplit 4
__global__ void k_lstm(const float* __restrict__ h0, const float* __restrict__ c0,
                       const float* __restrict__ Wih, const float* __restrict__ bih,
                       const float* __restrict__ Whh, const float* __restrict__ bhh,
                       float* __restrict__ ws, float* __restrict__ out){
  __shared__ float xh[4*384];        // 6 KB  [bl][ x(128) | h0(256) ]
  __shared__ float red[3*64*4];      // 3 KB
  int tid = threadIdx.x;
  int jc = (blockIdx.x & 15)*16, bc = (blockIdx.x >> 4)*4;
  for(int f=tid; f<4*384; f+=256){
    int bl = f/384, r = f - bl*384;
    xh[f] = (r < EE) ? ws[OFF_X + (bc+bl)*EE + r] : h0[(bc+bl)*HH + (r-EE)];
  }
  __syncthreads();
  int jl = tid & 15, bl = (tid >> 4) & 3, kq = tid >> 6;
  int j = jc + jl, b = bc + bl;
  float a0=0.f, a1=0.f, a2=0.f, a3=0.f;
  const float* a = &xh[bl*384];
  for(int k=kq*96; k<kq*96+96; k++){
    float v = a[k];
    const float* w = (k < EE) ? &Wih[k*4*HH + j] : &Whh[(k-EE)*4*HH + j];
    a0 += v*w[0]; a1 += v*w[HH]; a2 += v*w[2*HH]; a3 += v*w[3*HH];
  }
  if(kq){
    float* r = &red[((kq-1)*64 + bl*16 + jl)*4];
    r[0]=a0; r[1]=a1; r[2]=a2; r[3]=a3;
  }
  __syncthreads();
  if(kq==0){
    #pragma unroll
    for(int p=0;p<3;p++){
      const float* r = &red[(p*64 + bl*16 + jl)*4];
      a0+=r[0]; a1+=r[1]; a2+=r[2]; a3+=r[3];
    }
    a0 += bih[j] + bhh[j];
    a1 += bih[j+HH] + bhh[j+HH];
    a2 += bih[j+2*HH] + bhh[j+2*HH];
    a3 += bih[j+3*HH] + bhh[j+3*HH];
    float c = sigm(a1)*c0[b*HH+j] + sigm(a0)*tanhf(a2);
    float h = sigm(a3)*tanhf(c);
    out[O_H + b*HH + j] = h;
    out[O_C + b*HH + j] = c;
    ws[OFF_ST + b*HH2 + j]      = h;
    ws[OFF_ST + b*HH2 + HH + j] = c;
  }
}

// ------------------------------------------------------------------
// sd/wd projections.  grid 128 x 256: blocks 0-63 SD, 64-127 WD.
// block = 8 cols x 16 b, ksplit 2.
__global__ void k_proj(const float* __restrict__ Wdsec, const float* __restrict__ bdsec,
                       const float* __restrict__ Wdw,  const float* __restrict__ bdw,
                       float* __restrict__ ws){
  __shared__ float st[BB*HH2];   // 32 KB
  __shared__ float red[128];
  int tid = threadIdx.x;
  for(int f=tid; f<BB*HH2; f+=256) st[f] = ws[OFF_ST + f];
  __syncthreads();
  int mi = blockIdx.x >> 6;
  int c = (blockIdx.x & 63)*8 + (tid & 7);
  int bl = (tid >> 3) & 15;
  int kq = tid >> 7;   // 0..1
  const float* Wm = mi ? Wdw : Wdsec;
  const float* bias = mi ? bdw : bdsec;
  int dst = mi ? OFF_WD : OFF_SD;
  float acc = 0.0f;
  const float* a = &st[bl*HH2];
  for(int k=kq*256; k<kq*256+256; k++) acc += a[k]*Wm[k*HH2 + c];
  if(kq==1) red[bl*8 + (tid&7)] = acc;
  __syncthreads();
  if(kq==0) ws[dst + bl*HH2 + c] = acc + red[bl*8 + (tid&7)] + bias[c];
}

// ------------------------------------------------------------------
// k_gemm6 blocks 0..799: 64 rows x 512 cols, K=512, BK=32 single-buffered.
//   sc_w[row] = sum_n tanh(enc[row,:]@Whw[:,n] + wd[b,n] + cov[row]*Wcw[n]) * vw[n]
// blocks 800..927: section attention -> plain store SCSEC.
// grid 928 x 512, 36 KB static LDS -> 2 blocks/CU (16 waves).
__global__ __launch_bounds__(512, 4) void k_gemm6(
        const float* __restrict__ A, const unsigned short* __restrict__ Btg,
        const float* __restrict__ Wcw, const float* __restrict__ vw,
        const float* __restrict__ cover,
        const float* __restrict__ sec, const float* __restrict__ Whsec,
        const float* __restrict__ vsec, float* __restrict__ ws){
  __shared__ __align__(16) unsigned short smem[18432];   // 36 KB
  int tid = threadIdx.x;
  if(blockIdx.x >= GEMM_NB){
    // ---- esec: one block per (b,s) row ----
    float* row = (float*)smem;            // 512 floats
    float* red = row + HH2;               // 8
    int bi = blockIdx.x - GEMM_NB;        // 0..127
    int b = bi >> 3;
    if(tid < HH2) row[tid] = sec[(size_t)bi*HH2 + tid];
    __syncthreads();
    int col = tid;                        // 0..511
    float acc = 0.0f;
    #pragma unroll 8
    for(int k=0;k<HH2;k++) acc += row[k]*Whsec[k*HH2 + col];
    float val = tanhf(acc + ws[OFF_SD + b*HH2 + col]) * vsec[col];
    val = wave_sum(val);
    if((tid&63)==0) red[tid>>6] = val;
    __syncthreads();
    if(tid==0){
      float s = 0.0f;
      #pragma unroll
      for(int i=0;i<8;i++) s += red[i];
      ws[OFF_SCSEC + bi] = s;
    }
    return;
  }
  // ---- gemm ----
  unsigned short* As = smem;          // 64 rows x 4 kg: (row*4 + kg^)*8 shorts = 2048 sh (4KB)
  unsigned short* Bs = smem + 2048;   // 512 cols x 4 kg: (col*4 + kg^)*8 = 16384 sh (32KB)
  int w = tid >> 6, lane = tid & 63, m = lane & 15, q = lane >> 4;
  int mk = (m >> 1) & 3;              // swizzle key for reads
  int rg = w >> 1, cg = w & 1;        // 4 row-groups x 2 col-halves
  int row0 = blockIdx.x * 64;
  int b = blockIdx.x / 50;            // 50 blocks per batch (64*50 = 3200)
  float cov[4];
  #pragma unroll
  for(int r=0;r<4;r++) cov[r] = cover[row0 + rg*16 + q*4 + r];
  f32x4 acc[16];
  #pragma unroll
  for(int j=0;j<16;j++) acc[j] = (f32x4){0.f,0.f,0.f,0.f};

  int arow = tid >> 2, akg = tid & 3;   // A staging (tid<256): 256 units
  int bcol = tid;                       // B staging: col = tid, kg = i

  for(int rnd=0; rnd<16; rnd++){
    int k0 = rnd*32;
    if(tid < 256){
      const float4* src = (const float4*)&A[(size_t)(row0+arow)*HH2 + k0 + akg*8];
      float4 v0 = src[0], v1 = src[1];
      union{ bf16x8 v; unsigned short u[8]; } t;
      t.u[0]=f2b(v0.x); t.u[1]=f2b(v0.y); t.u[2]=f2b(v0.z); t.u[3]=f2b(v0.w);
      t.u[4]=f2b(v1.x); t.u[5]=f2b(v1.y); t.u[6]=f2b(v1.z); t.u[7]=f2b(v1.w);
      *(bf16x8*)&As[(arow*4 + (akg ^ ((arow>>1)&3)))*8] = t.v;
    }
    #pragma unroll
    for(int i=0;i<4;i++){
      bf16x8 bv = *(const bf16x8*)&Btg[((size_t)(rnd*4+i)*HH2 + bcol)*8];
      *(bf16x8*)&Bs[(bcol*4 + (i ^ ((bcol>>1)&3)))*8] = bv;
    }
    __syncthreads();
    bf16x8 af = *(bf16x8*)&As[((rg*16+m)*4 + (q ^ mk))*8];
    #pragma unroll
    for(int j=0;j<16;j++){
      int col = cg*256 + j*16 + m;
      bf16x8 bfv = *(bf16x8*)&Bs[(col*4 + (q ^ mk))*8];
      acc[j] = __builtin_amdgcn_mfma_f32_16x16x32_bf16(af, bfv, acc[j], 0,0,0);
    }
    __syncthreads();
  }
  // epilogue: fold cols with tanh into per-row sums
  float rsum[4] = {0,0,0,0};
  #pragma unroll
  for(int j=0;j<16;j++){
    int col = cg*256 + j*16 + m;
    float wdv = ws[OFF_WD + b*HH2 + col];
    float wcv = Wcw[col], vwv = vw[col];
    #pragma unroll
    for(int r=0;r<4;r++)
      rsum[r] += tanhf(acc[j][r] + wdv + cov[r]*wcv) * vwv;
  }
  float* rbuf = (float*)smem;   // 128 floats; safe after final barrier
  #pragma unroll
  for(int r=0;r<4;r++){
    float v = rsum[r];
    v += __shfl_xor(v,1,16); v += __shfl_xor(v,2,16);
    v += __shfl_xor(v,4,16); v += __shfl_xor(v,8,16);
    if(m==0) rbuf[cg*64 + rg*16 + q*4 + r] = v;
  }
  __syncthreads();
  if(tid < 64) ws[OFF_SCW + row0 + tid] = rbuf[tid] + rbuf[64 + tid];
}

// ------------------------------------------------------------------
// beta (inline) + attn softmax + mask + renorm + coverage out.  grid 16 x 256
__global__ void k_attn(const float* __restrict__ mask, const float* __restrict__ cover,
                       float* __restrict__ ws, float* __restrict__ out){
  int b = blockIdx.x, tid = threadIdx.x;
  __shared__ float vals[STK];
  __shared__ float red[4];
  __shared__ float sc[SS];
  if(tid < SS) sc[tid] = ws[OFF_SCSEC + b*SS + tid];
  __syncthreads();
  float bm = -1e30f;
  #pragma unroll
  for(int s=0;s<SS;s++) bm = fmaxf(bm, sc[s]);
  float be[SS]; float bsum = 0.0f;
  #pragma unroll
  for(int s=0;s<SS;s++){ be[s] = expf(sc[s]-bm); bsum += be[s]; }
  #pragma unroll
  for(int s=0;s<SS;s++) be[s] /= bsum;
  int lane = tid & 63, w = tid >> 6;
  float m = -1e30f;
  for(int j=tid;j<STK;j+=256){
    float v = be[j/TKK] * ws[OFF_SCW + b*STK + j];
    vals[j] = v; m = fmaxf(m, v);
  }
  m = wave_max(m);
  if(lane==0) red[w] = m;
  __syncthreads();
  m = fmaxf(fmaxf(red[0],red[1]), fmaxf(red[2],red[3]));
  __syncthreads();
  float ssum = 0.0f;
  for(int j=tid;j<STK;j+=256){
    float e = expf(vals[j]-m) * mask[b*STK + j];
    vals[j] = e; ssum += e;
  }
  ssum = wave_sum(ssum);
  if(lane==0) red[w] = ssum;
  __syncthreads();
  float inv = 1.0f/(red[0]+red[1]+red[2]+red[3]);
  for(int j=tid;j<STK;j+=256){
    float a = vals[j]*inv;
    out[O_ATTN + b*STK + j] = a;
    out[O_COV  + b*STK + j] = cover[b*STK + j] + a;
  }
}

// ------------------------------------------------------------------
// c_t = attn @ enc.  grid (50,16) x 256, atomic accumulate into CT
__global__ void k_ct(const float* __restrict__ enc, const float* __restrict__ out,
                     float* __restrict__ ws){
  int b = blockIdx.y, tid = threadIdx.x;
  __shared__ float a[64];
  int t0 = blockIdx.x*64;
  if(tid<64) a[tid] = out[O_ATTN + b*STK + t0 + tid];
  __syncthreads();
  float acc0=0.0f, acc1=0.0f;
  #pragma unroll 4
  for(int tt=0;tt<64;tt++){
    const float* row = &enc[(size_t)(b*STK + t0 + tt)*HH2];
    float av = a[tt];
    acc0 += av*row[tid];
    acc1 += av*row[256+tid];
  }
  atomicAdd(&ws[OFF_CT + b*HH2 + tid],       acc0);
  atomicAdd(&ws[OFF_CT + b*HH2 + 256 + tid], acc1);
}

// ------------------------------------------------------------------
// out1: grid 65 x 256. blocks 0..63: 4 cols x 16 b, ksplit 4.
// block 64: p_gen (4 waves x 4 b each) + c_t output copy.
__global__ void k_out1(const float* __restrict__ Wp, const float* __restrict__ bp,
                       const float* __restrict__ Wo1, const float* __restrict__ bo1,
                       float* __restrict__ ws, float* __restrict__ out){
  __shared__ float cat[BB*768];   // 48 KB  [b][ h(256) | ct(512) ]
  __shared__ float red[3*64];
  int tid = threadIdx.x;
  if(blockIdx.x == 64){
    int w = tid >> 6, lane = tid & 63;
    #pragma unroll
    for(int i=0;i<4;i++){
      int b = w*4 + i;
      float p = 0.0f;
      for(int k=lane;k<4*HH+EE;k+=64){
        float val = (k < HH2) ? ws[OFF_CT + b*HH2 + k]
                  : (k < 4*HH) ? ws[OFF_ST + b*HH2 + (k-HH2)]
                  : ws[OFF_X + b*EE + (k-4*HH)];
        p += val * Wp[k];
      }
      p = wave_sum(p);
      if(lane==0){
        float pg = sigm(p + bp[0]);
        ws[OFF_PGEN + b] = pg;
        out[O_PGEN + b]  = pg;
      }
    }
    for(int f=tid; f<BB*HH2; f+=256) out[O_CT + f] = ws[OFF_CT + f];
    return;
  }
  for(int f=tid; f<BB*768; f+=256){
    int b = f/768, r = f - b*768;
    cat[f] = (r < HH) ? ws[OFF_ST + b*HH2 + r] : ws[OFF_CT + b*HH2 + (r-HH)];
  }
  __syncthreads();
  int cl = tid & 3, bl = (tid >> 2) & 15, kq = tid >> 6;
  int c = blockIdx.x*4 + cl;
  float acc = 0.0f;
  const float* a = &cat[bl*768];
  for(int k=kq*192; k<kq*192+192; k++) acc += a[k]*Wo1[k*HH + c];
  if(kq) red[(kq-1)*64 + bl*4 + cl] = acc;
  __syncthreads();
  if(kq==0){
    acc += red[bl*4+cl] + red[64 + bl*4+cl] + red[128 + bl*4+cl];
    ws[OFF_OUT1 + bl*HH + c] = acc + bo1[c];
  }
}

// ------------------------------------------------------------------
// logits -> exp (logits tiny, no max needed) + per-block PSUM.  grid 782 x 256
__global__ void k_logits(const float* __restrict__ W2, const float* __restrict__ b2,
                         float* __restrict__ ws, float* __restrict__ out){
  int tid = threadIdx.x;
  int c = blockIdx.x*64 + (tid & 63);
  int bq = tid >> 6;                 // 0..3 -> b = bq*4..bq*4+3
  __shared__ float o1[BB*HH];        // 16 KB
  for(int i=tid;i<BB*HH;i+=256) o1[i] = ws[OFF_OUT1 + i];
  __syncthreads();
  bool ok = c < VV;
  float acc[4] = {0,0,0,0};
  if(ok){
    for(int k=0;k<HH;k++){
      float wv = W2[(size_t)k*VV + c];
      #pragma unroll
      for(int i=0;i<4;i++) acc[i] += o1[(bq*4+i)*HH + k]*wv;
    }
  }
  float bias = ok ? b2[c] : 0.0f;
  int lane = tid & 63;
  #pragma unroll
  for(int i=0;i<4;i++){
    float e = ok ? expf(acc[i]+bias) : 0.0f;
    if(ok) out[(size_t)(bq*4+i)*VOO + c] = e;
    float sv = wave_sum(e);
    if(lane==0) ws[OFF_PSUM + blockIdx.x*BB + bq*4 + i] = sv;
  }
}

// ------------------------------------------------------------------
// final_dist = p_gen * e / sum (v<V), extra_zeros tail.  grid (196,16) x 256
__global__ void k_final(const float* __restrict__ xz, float* __restrict__ ws,
                        float* __restrict__ out){
  int b = blockIdx.y;
  int v = blockIdx.x*256 + threadIdx.x;
  __shared__ float red[4];
  int lane = threadIdx.x & 63, w = threadIdx.x >> 6;
  float p = 0.0f;
  for(int i=threadIdx.x;i<NLBLK;i+=256) p += ws[OFF_PSUM + i*BB + b];
  p = wave_sum(p);
  if(lane==0) red[w] = p;
  __syncthreads();
  float s = red[0]+red[1]+red[2]+red[3];
  float pg = ws[OFF_PGEN + b];
  if(v < VV)       out[(size_t)b*VOO + v] = pg * out[(size_t)b*VOO + v] / s;
  else if(v < VOO) out[(size_t)b*VOO + v] = xz[b*OOVV + (v-VV)];
}

// ------------------------------------------------------------------
// scatter-add (1-p_gen)*attn at extend-vocab indices.  grid 16 x 256
__global__ void k_scatter(const int* __restrict__ ebev, float* __restrict__ ws,
                          float* __restrict__ out){
  int b = blockIdx.x;
  float r = 1.0f - ws[OFF_PGEN + b];
  for(int j=threadIdx.x;j<STK;j+=256){
    int idx = ebev[b*STK + j];
    atomicAdd(&out[(size_t)b*VOO + idx], r*out[O_ATTN + b*STK + j]);
  }
}

extern "C" void kernel_launch(void* const* d_in, const int* in_sizes, int n_in,
                              void* d_out, int out_size, void* d_ws, size_t ws_size,
                              hipStream_t stream){
  const int*   y     = (const int*)  d_in[0];
  const float* h0    = (const float*)d_in[1];
  const float* c0    = (const float*)d_in[2];
  const float* enc   = (const float*)d_in[3];
  const float* sec   = (const float*)d_in[4];
  const float* mask  = (const float*)d_in[5];
  const float* ct1   = (const float*)d_in[6];
  const float* xz    = (const float*)d_in[7];
  const int*   ebev  = (const int*)  d_in[8];
  const float* cover = (const float*)d_in[9];
  /* d_in[10] = gamma (unused by reference) */
  const float* emb   = (const float*)d_in[11];
  const float* Wxc   = (const float*)d_in[12];
  const float* bxc   = (const float*)d_in[13];
  const float* Wih   = (const float*)d_in[14];
  const float* bih   = (const float*)d_in[15];
  const float* Whh   = (const float*)d_in[16];
  const float* bhh   = (const float*)d_in[17];
  const float* Whsec = (const float*)d_in[18];
  const float* Wdsec = (const float*)d_in[19];
  const float* bdsec = (const float*)d_in[20];
  const float* vsec  = (const float*)d_in[21];
  const float* Whw   = (const float*)d_in[22];
  const float* Wcw   = (const float*)d_in[23];
  const float* Wdw   = (const float*)d_in[24];
  const float* bdw   = (const float*)d_in[25];
  const float* vw    = (const float*)d_in[26];
  const float* Wp    = (const float*)d_in[27];
  const float* bp    = (const float*)d_in[28];
  const float* Wo1   = (const float*)d_in[29];
  const float* bo1   = (const float*)d_in[30];
  const float* Wo2   = (const float*)d_in[31];
  const float* bo2   = (const float*)d_in[32];
  float* out = (float*)d_out;
  float* ws  = (float*)d_ws;
  unsigned short* Btg = (unsigned short*)(ws + OFF_BT);

  k_pre    <<<dim3(81),       dim3(256), 0, stream>>>(Whw, Btg, y, ct1, emb, Wxc, bxc, ws);
  k_lstm   <<<dim3(64),       dim3(256), 0, stream>>>(h0, c0, Wih, bih, Whh, bhh, ws, out);
  k_proj   <<<dim3(128),      dim3(256), 0, stream>>>(Wdsec, bdsec, Wdw, bdw, ws);
  k_gemm6  <<<dim3(928),      dim3(512), 0, stream>>>(enc, Btg, Wcw, vw, cover, sec, Whsec, vsec, ws);
  k_attn   <<<dim3(BB),       dim3(256), 0, stream>>>(mask, cover, ws, out);
  k_ct     <<<dim3(50,BB),    dim3(256), 0, stream>>>(enc, out, ws);
  k_out1   <<<dim3(65),       dim3(256), 0, stream>>>(Wp, bp, Wo1, bo1, ws, out);
  k_logits <<<dim3(NLBLK),    dim3(256), 0, stream>>>(Wo2, bo2, ws, out);
  k_final  <<<dim3(196,BB),   dim3(256), 0, stream>>>(xz, ws, out);
  k_scatter<<<dim3(BB),       dim3(256), 0, stream>>>(ebev, ws, out);
}